// Round 7
// baseline (2452.790 us; speedup 1.0000x reference)
//
#include <hip/hip_runtime.h>
#include <cmath>

// Problem constants
#define IN_DIM   256
#define H0_DIM   512
#define H1_DIM   256
#define BOT      128
#define NQ_      131072
#define NE_      262144
#define SEQ_     262144
#define QWIN     32768
#define NWIN     (NQ_/QWIN)
#define PE_K     384          // PE cols 384..511 are constant -> folded into bias

// Workspace layout (bytes), ws = 1 GiB.
static const size_t OFF_XH    = 0;            // 262144*256*2 = 134217728
static const size_t OFF_XL    = 134217728;
static const size_t OFF_Z     = 268435456;    // 131072*512*4 = 268435456
static const size_t OFF_PEH   = 536870912;    // 32768*384*2 = 25165824
static const size_t OFF_PEL   = 562036736;
static const size_t OFF_H2    = 738197504;    // 262144*128*4 = 134217728
static const size_t OFF_W0AH  = 872415232;    // [512][256] 262144
static const size_t OFF_W0AL  = 872677376;
static const size_t OFF_W0BH  = 872939520;    // [512][384] 393216
static const size_t OFF_W0BL  = 873332736;
static const size_t OFF_W1H   = 873725952;    // [256][512] 262144
static const size_t OFF_W1L   = 873988096;
static const size_t OFF_W2H   = 874250240;    // [128][256] 65536
static const size_t OFF_W2L   = 874315776;
static const size_t OFF_PW0H  = 874381312;    // [256][128] 65536
static const size_t OFF_PW0L  = 874446848;
static const size_t OFF_BCONST= 874512384;    // 512*4
static const size_t OFF_START = 874514432;    // (NQ+1)*4
// post-loop aliases
static const size_t OFF_MEANH = 0;            // alias xH (dead after fused edge kernel)
static const size_t OFF_MEANL = 33554432;
static const size_t OFF_G1    = 268435456;    // alias Z (dead after fused edge kernel)

typedef __attribute__((ext_vector_type(8))) short bf16x8;
typedef __attribute__((ext_vector_type(4))) float f32x4;

__device__ __forceinline__ float gelu_f(float v) {
    return v * 0.5f * (1.0f + erff(v * 0.7071067811865476f));
}
__device__ __forceinline__ unsigned short f2bf(float f) {
    unsigned int u = __float_as_uint(f);
    unsigned int r = (u + 0x7FFFu + ((u >> 16) & 1u)) >> 16;
    return (unsigned short)r;
}
__device__ __forceinline__ float bf2f(unsigned short h) {
    return __uint_as_float(((unsigned int)h) << 16);
}
__device__ __forceinline__ unsigned int pack2(unsigned short a, unsigned short b) {
    return (unsigned int)a | ((unsigned int)b << 16);
}
__device__ __forceinline__ void stage16(const void* g, void* l) {
    __builtin_amdgcn_global_load_lds(
        (const __attribute__((address_space(1))) unsigned int*)g,
        (__attribute__((address_space(3))) unsigned int*)l,
        16, 0, 0);
}
// float4 -> 2x(hi pair) + 2x(lo pair)
__device__ __forceinline__ void cvt4(const float4 v, unsigned int* hw, unsigned int* lw) {
    const unsigned short a = f2bf(v.x), b = f2bf(v.y), c = f2bf(v.z), d = f2bf(v.w);
    hw[0] = pack2(a, b); hw[1] = pack2(c, d);
    lw[0] = pack2(f2bf(v.x - bf2f(a)), f2bf(v.y - bf2f(b)));
    lw[1] = pack2(f2bf(v.z - bf2f(c)), f2bf(v.w - bf2f(d)));
}

// ---------------------------------------------------------------------------
// x fp32 [SEQ][256] -> xH/xL bf16 (wave per row)
// ---------------------------------------------------------------------------
__global__ __launch_bounds__(256) void conv_x(
    const float* __restrict__ x,
    unsigned short* __restrict__ xH, unsigned short* __restrict__ xL)
{
    const int wv = threadIdx.x >> 6;
    const int l  = threadIdx.x & 63;
    const int row = blockIdx.x * 4 + wv;
    const size_t base = (size_t)row * IN_DIM + l * 4;
    float4 v = *(const float4*)&x[base];
    unsigned short h0 = f2bf(v.x), h1 = f2bf(v.y), h2 = f2bf(v.z), h3 = f2bf(v.w);
    uint2 H, L;
    H.x = pack2(h0, h1); H.y = pack2(h2, h3);
    L.x = pack2(f2bf(v.x - bf2f(h0)), f2bf(v.y - bf2f(h1)));
    L.y = pack2(f2bf(v.z - bf2f(h2)), f2bf(v.w - bf2f(h3)));
    *(uint2*)&xH[base] = H;
    *(uint2*)&xL[base] = L;
}

// ---------------------------------------------------------------------------
// Weight convert: W[K][N] fp32 -> WT hi/lo bf16 [N][K]
// ---------------------------------------------------------------------------
__global__ __launch_bounds__(256) void conv_w(
    const float* __restrict__ W, unsigned short* __restrict__ WTh,
    unsigned short* __restrict__ WTl, int K, int N)
{
    int idx = blockIdx.x * 256 + threadIdx.x;
    if (idx >= K * N) return;
    int k = idx / N, n = idx % N;
    float v = W[idx];
    unsigned short h = f2bf(v);
    WTh[(size_t)n * K + k] = h;
    WTl[(size_t)n * K + k] = f2bf(v - bf2f(h));
}

// ---------------------------------------------------------------------------
// bconst[n] = b0[n] + sum_j sin(om_j)*w0[640+j][n] + cos(om_j)*w0[704+j][n]
// ---------------------------------------------------------------------------
__global__ __launch_bounds__(256) void bias_fold(
    const float* __restrict__ w0, const float* __restrict__ b0,
    float* __restrict__ bconst)
{
    int n = blockIdx.x * 256 + threadIdx.x;
    if (n >= H0_DIM) return;
    float s = b0[n];
    for (int j = 0; j < 64; ++j) {
        float om = exp2f((float)j * (-13.287712379549449f / 64.0f));
        s += sinf(om) * w0[(size_t)(640 + j) * H0_DIM + n];
        s += cosf(om) * w0[(size_t)(704 + j) * H0_DIM + n];
    }
    bconst[n] = s;
}

// ---------------------------------------------------------------------------
// start[q] = first edge index with qidx >= q (qidx sorted ascending)
// ---------------------------------------------------------------------------
__global__ __launch_bounds__(256) void seg_offsets(
    const int* __restrict__ edges, int* __restrict__ start)
{
    int e = blockIdx.x * 256 + threadIdx.x;
    if (e > NE_) return;
    int qc = (e < NE_) ? edges[2 * e] : NQ_;
    int qp = (e > 0) ? edges[2 * e - 2] : -1;
    for (int q = qp + 1; q <= qc; ++q) start[q] = e;
}

// ---------------------------------------------------------------------------
// PE build for window: rows i in [0,QWIN), query q = qbase+i, cols 0..383.
// ---------------------------------------------------------------------------
__global__ __launch_bounds__(256) void build_pe(
    const float* __restrict__ qpos, int qbase,
    unsigned short* __restrict__ peH, unsigned short* __restrict__ peL)
{
    const int wv = threadIdx.x >> 6;
    const int l  = threadIdx.x & 63;
    const int i  = blockIdx.x * 4 + wv;
    const int i0 = l * 8;
    if (i0 >= PE_K) return;
    const int q  = qbase + i;
    const size_t base = (size_t)i * PE_K;

    const int cc = i0 >> 7;          // coord 0..2
    const int j0 = i0 & 127;
    const float cv = qpos[q * 3 + cc] * 0.01f - 1.0f;
    const bool is_sin = (j0 < 64);
    const int jj0 = j0 & 63;
    unsigned int hw[4], lw[4];
    #pragma unroll
    for (int p2 = 0; p2 < 4; ++p2) {
        unsigned short hh[2], ll[2];
        #pragma unroll
        for (int s = 0; s < 2; ++s) {
            int jj = jj0 + p2 * 2 + s;
            float om  = exp2f((float)jj * (-13.287712379549449f / 64.0f));
            float arg = cv * om;
            float v   = is_sin ? __sinf(arg) : __cosf(arg);
            unsigned short h = f2bf(v);
            hh[s] = h; ll[s] = f2bf(v - bf2f(h));
        }
        hw[p2] = pack2(hh[0], hh[1]);
        lw[p2] = pack2(ll[0], ll[1]);
    }
    uint4 H, L;
    H.x = hw[0]; H.y = hw[1]; H.z = hw[2]; H.w = hw[3];
    L.x = lw[0]; L.y = lw[1]; L.z = lw[2]; L.w = lw[3];
    *(uint4*)&peH[base + i0] = H;
    *(uint4*)&peL[base + i0] = L;
}

// ---------------------------------------------------------------------------
// Split-bf16 MFMA GEMM (3 passes AhBh+AhBl+AlBh). 128x128 tile, BK=32.
// R2's proven structure: A and B both LDS-staged (8x stage16/step), 2-barrier
// K-loop. Used for the Z build (PE @ W0b') and the pred0 GEMM.
// ---------------------------------------------------------------------------
template <int ACT, int OUT_MODE, int GATHER>
__global__ __launch_bounds__(256) void gemm_mfma(
    const unsigned short* __restrict__ Ah, const unsigned short* __restrict__ Al,
    const unsigned short* __restrict__ Bh, const unsigned short* __restrict__ Bl,
    const float* __restrict__ bias,
    float* __restrict__ Cf, unsigned short* __restrict__ ChO, unsigned short* __restrict__ ClO,
    int M, int K, int N,
    const int* __restrict__ gp, const float* __restrict__ Zw)
{
    __shared__ __align__(16) short lds[4][128][32];   // 32 KB

    const int tid = threadIdx.x;
    const int w   = tid >> 6;
    const int l   = tid & 63;
    const int l16 = l & 15;
    const int lq  = l >> 4;
    const int bm  = blockIdx.y * 128;
    const int bn  = blockIdx.x * 128;
    const int wm  = (w & 1) * 64;
    const int wn  = (w >> 1) * 64;

    f32x4 acc[4][4];
    #pragma unroll
    for (int i = 0; i < 4; ++i)
        #pragma unroll
        for (int j = 0; j < 4; ++j)
            acc[i][j] = (f32x4){0.f, 0.f, 0.f, 0.f};

    const int jrow = l >> 2;
    const int jkc  = l & 3;
    const int t0 = w * 2, t1 = t0 + 1;
    const int r0 = t0 * 16 + jrow, r1 = t1 * 16 + jrow;

    size_t arow0, arow1;
    if (GATHER) {
        arow0 = (size_t)gp[2 * (bm + r0) + 1] * K;
        arow1 = (size_t)gp[2 * (bm + r1) + 1] * K;
    } else {
        arow0 = (size_t)(bm + r0) * K;
        arow1 = (size_t)(bm + r1) * K;
    }
    const size_t brow0 = (size_t)(bn + r0) * K;
    const size_t brow1 = (size_t)(bn + r1) * K;
    short* d00 = &lds[0][0][0] + t0 * 512;
    short* d01 = &lds[1][0][0] + t0 * 512;
    short* d02 = &lds[2][0][0] + t0 * 512;
    short* d03 = &lds[3][0][0] + t0 * 512;
    short* d10 = &lds[0][0][0] + t1 * 512;
    short* d11 = &lds[1][0][0] + t1 * 512;
    short* d12 = &lds[2][0][0] + t1 * 512;
    short* d13 = &lds[3][0][0] + t1 * 512;

    for (int k0 = 0; k0 < K; k0 += 32) {
        const int ko = k0 + jkc * 8;
        stage16(Ah + arow0 + ko, d00);
        stage16(Al + arow0 + ko, d01);
        stage16(Bh + brow0 + ko, d02);
        stage16(Bl + brow0 + ko, d03);
        stage16(Ah + arow1 + ko, d10);
        stage16(Al + arow1 + ko, d11);
        stage16(Bh + brow1 + ko, d12);
        stage16(Bl + brow1 + ko, d13);
        __syncthreads();

        bf16x8 ah[4], al[4], bh[4], bl[4];
        #pragma unroll
        for (int i = 0; i < 4; ++i) {
            ah[i] = *(const bf16x8*)&lds[0][wm + i*16 + l16][lq*8];
            al[i] = *(const bf16x8*)&lds[1][wm + i*16 + l16][lq*8];
            bh[i] = *(const bf16x8*)&lds[2][wn + i*16 + l16][lq*8];
            bl[i] = *(const bf16x8*)&lds[3][wn + i*16 + l16][lq*8];
        }
        #pragma unroll
        for (int i = 0; i < 4; ++i)
            #pragma unroll
            for (int j = 0; j < 4; ++j) {
                acc[i][j] = __builtin_amdgcn_mfma_f32_16x16x32_bf16(ah[i], bh[j], acc[i][j], 0, 0, 0);
                acc[i][j] = __builtin_amdgcn_mfma_f32_16x16x32_bf16(ah[i], bl[j], acc[i][j], 0, 0, 0);
                acc[i][j] = __builtin_amdgcn_mfma_f32_16x16x32_bf16(al[i], bh[j], acc[i][j], 0, 0, 0);
            }
        __syncthreads();
    }

    if (OUT_MODE == 0) {
        #pragma unroll
        for (int j = 0; j < 4; ++j) {
            int n = bn + wn + j * 16 + l16;
            float bv = bias[n];
            #pragma unroll
            for (int i = 0; i < 4; ++i) {
                int mrow = bm + wm + i * 16 + lq * 4;
                #pragma unroll
                for (int r = 0; r < 4; ++r) {
                    float v = acc[i][j][r] + bv;
                    if (ACT) v = gelu_f(v);
                    Cf[(size_t)(mrow + r) * N + n] = v;
                }
            }
        }
    }
}

// ---------------------------------------------------------------------------
// FUSED edge MLP, v7: R6 structure with the spill fixed. The h1/h2 K-loops
// are forced ROLLED (#pragma unroll 1): fully-unrolled versions let the
// scheduler hoist 4 iterations of global B-fragment loads -> 128 extra live
// VGPRs -> scratch spill (R6: WRITE 245 MB, FETCH 871 MB). Rolled keeps one
// iteration's fragments live (~190 total regs, fits the (256,2) cap).
//   - phase 1: acc1[4][2], K=256; only gathered x staged in LDS; W0a -> VGPR.
//   - h1: h1acc[4][4]; A = h0 from LDS, B = W1 global. ZERO barriers.
//   - h2: acc2[4][2]; A = gelu(h1+b1) transposed into h0 bufs, B = W2 global.
// LDS 48 KB: stage/lbuf 16 KB + h0h 16 KB + h0l 16 KB.
// ---------------------------------------------------------------------------
__global__ __launch_bounds__(256, 2) void fused_edge(
    const unsigned short* __restrict__ xHg, const unsigned short* __restrict__ xLg,
    const unsigned short* __restrict__ w0aHg, const unsigned short* __restrict__ w0aLg,
    const unsigned short* __restrict__ w1Hg, const unsigned short* __restrict__ w1Lg,
    const unsigned short* __restrict__ w2Hg, const unsigned short* __restrict__ w2Lg,
    const float* __restrict__ Zg, const float* __restrict__ b1g,
    const float* __restrict__ b2g, const int* __restrict__ gp,
    float* __restrict__ h2g)
{
    extern __shared__ __align__(16) short smem[];
    // region [0, 8192): A stage [64][32] hi@0 lo@2048 (8 KB) / lbuf alias (16 KB)
    short* h0h = smem + 8192;    // [64][128] = 16 KB
    short* h0l = smem + 16384;   // 16 KB

    const int tid = threadIdx.x;
    const int w   = tid >> 6;
    const int l   = tid & 63;
    const int l16 = l & 15;
    const int lq  = l >> 4;
    const int bm  = blockIdx.x * 64;

    const int wn_p = w * 32;   // phase-1 / h2 col base
    const int wn1  = w * 64;   // h1 col base (0..255)

    // A staging: thread covers row rx = tid>>2, 16B unit ux = tid&3
    const int rx = tid >> 2;
    const int ux = tid & 3;
    const unsigned int xoff = (unsigned)gp[2 * (bm + rx) + 1] * 256u + ux * 8;
    const int q_e = gp[2 * (bm + l)];
    const unsigned int zq = (unsigned)q_e * 512u;
    float* lbuf = ((float*)smem) + w * 1024;   // per-wave [64][16] f32

    f32x4 h1acc[4][4];
    #pragma unroll
    for (int i = 0; i < 4; ++i)
        #pragma unroll
        for (int j = 0; j < 4; ++j)
            h1acc[i][j] = (f32x4){0.f, 0.f, 0.f, 0.f};

    const int rsw7 = l16 & 7;   // (row & 7) for fragment rows i*16+l16

    #pragma unroll 1
    for (int c = 0; c < 4; ++c) {
        f32x4 acc1[4][2];
        #pragma unroll
        for (int i = 0; i < 4; ++i)
            #pragma unroll
            for (int j = 0; j < 2; ++j)
                acc1[i][j] = (f32x4){0.f, 0.f, 0.f, 0.f};

        // ---- phase 1: h0c[64][128] = x[gidx] @ W0a_c, K=256 ----
        stage16(xHg + xoff, smem + tid * 8);
        stage16(xLg + xoff, smem + 2048 + tid * 8);
        __syncthreads();
        #pragma unroll 1
        for (int ks = 0; ks < 8; ++ks) {
            bf16x8 a_h[4], a_l[4], b_h[2], b_l[2];
            #pragma unroll
            for (int i = 0; i < 4; ++i) {
                const int ro = (i * 16 + l16) * 32 + lq * 8;
                a_h[i] = *(const bf16x8*)&smem[ro];
                a_l[i] = *(const bf16x8*)&smem[2048 + ro];
            }
            {
                const unsigned kk = (unsigned)(ks * 32 + lq * 8);
                #pragma unroll
                for (int j = 0; j < 2; ++j) {
                    const unsigned n = (unsigned)(c * 128 + wn_p + j * 16 + l16);
                    b_h[j] = *(const bf16x8*)&w0aHg[n * 256u + kk];
                    b_l[j] = *(const bf16x8*)&w0aLg[n * 256u + kk];
                }
            }
            __syncthreads();    // stage-region reads done
            if (ks < 7) {
                const int ko = (ks + 1) * 32;
                stage16(xHg + xoff + ko, smem + tid * 8);
                stage16(xLg + xoff + ko, smem + 2048 + tid * 8);
            }
            #pragma unroll
            for (int i = 0; i < 4; ++i)
                #pragma unroll
                for (int j = 0; j < 2; ++j) {
                    acc1[i][j] = __builtin_amdgcn_mfma_f32_16x16x32_bf16(a_h[i], b_h[j], acc1[i][j], 0, 0, 0);
                    acc1[i][j] = __builtin_amdgcn_mfma_f32_16x16x32_bf16(a_h[i], b_l[j], acc1[i][j], 0, 0, 0);
                    acc1[i][j] = __builtin_amdgcn_mfma_f32_16x16x32_bf16(a_l[i], b_h[j], acc1[i][j], 0, 0, 0);
                }
            __syncthreads();    // stage visible
        }

        // ---- epilogue: +Z, gelu, cvt -> h0h/h0l (per-wave lbuf) ----
        #pragma unroll 1
        for (int jj = 0; jj < 2; ++jj) {
            #pragma unroll
            for (int i = 0; i < 4; ++i)
                #pragma unroll
                for (int r = 0; r < 4; ++r) {
                    const int rowq = i * 16 + lq * 4 + r;
                    const int u = l16 >> 2;
                    lbuf[rowq * 16 + (((u ^ ((rowq >> 1) & 3)) << 2) | (l16 & 3))] = acc1[i][jj][r];
                }
            const unsigned zc = zq + (unsigned)(c * 128 + wn_p + jj * 16);
            unsigned int hw[8], lw[8];
            #pragma unroll
            for (int i4 = 0; i4 < 4; ++i4) {
                float4 v = *(const float4*)&lbuf[l * 16 + ((i4 ^ ((l >> 1) & 3)) << 2)];
                const float4 z = *(const float4*)&Zg[zc + i4 * 4];
                v.x = gelu_f(v.x + z.x); v.y = gelu_f(v.y + z.y);
                v.z = gelu_f(v.z + z.z); v.w = gelu_f(v.w + z.w);
                cvt4(v, &hw[i4 * 2], &lw[i4 * 2]);
            }
            const int cu0 = w * 4 + jj * 2;
            const int o0 = l * 128 + (((cu0    ) ^ (l & 7)) << 3);
            const int o1 = l * 128 + (((cu0 + 1) ^ (l & 7)) << 3);
            uint4 H0, H1, L0, L1;
            H0.x = hw[0]; H0.y = hw[1]; H0.z = hw[2]; H0.w = hw[3];
            H1.x = hw[4]; H1.y = hw[5]; H1.z = hw[6]; H1.w = hw[7];
            L0.x = lw[0]; L0.y = lw[1]; L0.z = lw[2]; L0.w = lw[3];
            L1.x = lw[4]; L1.y = lw[5]; L1.z = lw[6]; L1.w = lw[7];
            *(uint4*)&h0h[o0] = H0; *(uint4*)&h0h[o1] = H1;
            *(uint4*)&h0l[o0] = L0; *(uint4*)&h0l[o1] = L1;
        }
        __syncthreads();   // h0 sub-tile visible to all waves

        // ---- h1 partial: h1acc += h0c @ W1[c*128.., :], K=128, NO barriers ----
        // ROLLED: unrolling hoists 4 iterations of B global loads -> spill.
        #pragma unroll 1
        for (int ks2 = 0; ks2 < 4; ++ks2) {
            bf16x8 a_h[4], a_l[4], b_h[4], b_l[4];
            #pragma unroll
            for (int i = 0; i < 4; ++i) {
                const int ro = (i * 16 + l16) * 128 + (((ks2 * 4 + lq) ^ rsw7) << 3);
                a_h[i] = *(const bf16x8*)&h0h[ro];
                a_l[i] = *(const bf16x8*)&h0l[ro];
            }
            {
                const unsigned kk = (unsigned)(c * 128 + ks2 * 32 + lq * 8);
                #pragma unroll
                for (int j = 0; j < 4; ++j) {
                    const unsigned n = (unsigned)(wn1 + j * 16 + l16);
                    b_h[j] = *(const bf16x8*)&w1Hg[n * 512u + kk];
                    b_l[j] = *(const bf16x8*)&w1Lg[n * 512u + kk];
                }
            }
            #pragma unroll
            for (int i = 0; i < 4; ++i)
                #pragma unroll
                for (int j = 0; j < 4; ++j) {
                    h1acc[i][j] = __builtin_amdgcn_mfma_f32_16x16x32_bf16(a_h[i], b_h[j], h1acc[i][j], 0, 0, 0);
                    h1acc[i][j] = __builtin_amdgcn_mfma_f32_16x16x32_bf16(a_h[i], b_l[j], h1acc[i][j], 0, 0, 0);
                    h1acc[i][j] = __builtin_amdgcn_mfma_f32_16x16x32_bf16(a_l[i], b_h[j], h1acc[i][j], 0, 0, 0);
                }
        }
        // next c's staging happens after this loop; lbuf readers were
        // pre-barrier, so the alias is safe.
    }

    // ---- h2 = gelu(h1 + b1) @ W2 + b2, K=256 in two 128-col halves ----
    f32x4 acc2[4][2];
    #pragma unroll
    for (int i = 0; i < 4; ++i)
        #pragma unroll
        for (int j = 0; j < 2; ++j)
            acc2[i][j] = (f32x4){0.f, 0.f, 0.f, 0.f};

    #pragma unroll 1
    for (int kh = 0; kh < 2; ++kh) {
        const bool my = ((w >> 1) == kh);   // wave w owns h1 cols w*64..w*64+63
        __syncthreads();   // previous readers of h0 bufs done
        if (my) {
            #pragma unroll 1
            for (int jj = 0; jj < 4; ++jj) {
                const float bv = b1g[wn1 + jj * 16 + l16];
                #pragma unroll
                for (int i = 0; i < 4; ++i)
                    #pragma unroll
                    for (int r = 0; r < 4; ++r) {
                        const int rowq = i * 16 + lq * 4 + r;
                        const int u = l16 >> 2;
                        lbuf[rowq * 16 + (((u ^ ((rowq >> 1) & 3)) << 2) | (l16 & 3))] =
                            gelu_f(h1acc[i][jj][r] + bv);
                    }
                unsigned int hw[8], lw[8];
                #pragma unroll
                for (int i4 = 0; i4 < 4; ++i4) {
                    float4 v = *(const float4*)&lbuf[l * 16 + ((i4 ^ ((l >> 1) & 3)) << 2)];
                    cvt4(v, &hw[i4 * 2], &lw[i4 * 2]);
                }
                const int cu0 = (w & 1) * 8 + jj * 2;
                const int o0 = l * 128 + (((cu0    ) ^ (l & 7)) << 3);
                const int o1 = l * 128 + (((cu0 + 1) ^ (l & 7)) << 3);
                uint4 H0, H1, L0, L1;
                H0.x = hw[0]; H0.y = hw[1]; H0.z = hw[2]; H0.w = hw[3];
                H1.x = hw[4]; H1.y = hw[5]; H1.z = hw[6]; H1.w = hw[7];
                L0.x = lw[0]; L0.y = lw[1]; L0.z = lw[2]; L0.w = lw[3];
                L1.x = lw[4]; L1.y = lw[5]; L1.z = lw[6]; L1.w = lw[7];
                *(uint4*)&h0h[o0] = H0; *(uint4*)&h0h[o1] = H1;
                *(uint4*)&h0l[o0] = L0; *(uint4*)&h0l[o1] = L1;
            }
        }
        __syncthreads();   // h1 half visible

        // ROLLED for the same spill reason as the h1 loop.
        #pragma unroll 1
        for (int ks2 = 0; ks2 < 4; ++ks2) {
            bf16x8 a_h[4], a_l[4], b_h[2], b_l[2];
            #pragma unroll
            for (int i = 0; i < 4; ++i) {
                const int ro = (i * 16 + l16) * 128 + (((ks2 * 4 + lq) ^ rsw7) << 3);
                a_h[i] = *(const bf16x8*)&h0h[ro];
                a_l[i] = *(const bf16x8*)&h0l[ro];
            }
            {
                const unsigned kk = (unsigned)(kh * 128 + ks2 * 32 + lq * 8);
                #pragma unroll
                for (int j = 0; j < 2; ++j) {
                    const unsigned n = (unsigned)(wn_p + j * 16 + l16);
                    b_h[j] = *(const bf16x8*)&w2Hg[n * 256u + kk];
                    b_l[j] = *(const bf16x8*)&w2Lg[n * 256u + kk];
                }
            }
            #pragma unroll
            for (int i = 0; i < 4; ++i)
                #pragma unroll
                for (int j = 0; j < 2; ++j) {
                    acc2[i][j] = __builtin_amdgcn_mfma_f32_16x16x32_bf16(a_h[i], b_h[j], acc2[i][j], 0, 0, 0);
                    acc2[i][j] = __builtin_amdgcn_mfma_f32_16x16x32_bf16(a_h[i], b_l[j], acc2[i][j], 0, 0, 0);
                    acc2[i][j] = __builtin_amdgcn_mfma_f32_16x16x32_bf16(a_l[i], b_h[j], acc2[i][j], 0, 0, 0);
                }
        }
    }

    // ---- h2 epilogue: + b2, fp32 store ----
    #pragma unroll
    for (int j = 0; j < 2; ++j) {
        const int n = wn_p + j * 16 + l16;
        const float bv = b2g[n];
        #pragma unroll
        for (int i = 0; i < 4; ++i) {
            const int er = bm + i * 16 + lq * 4;
            #pragma unroll
            for (int r = 0; r < 4; ++r)
                h2g[(size_t)(er + r) * BOT + n] = acc2[i][j][r] + bv;
        }
    }
}

// ---------------------------------------------------------------------------
// segment mean via precomputed offsets
// ---------------------------------------------------------------------------
__global__ __launch_bounds__(256) void seg_mean(
    const int* __restrict__ start, const float* __restrict__ h2,
    unsigned short* __restrict__ mH, unsigned short* __restrict__ mL)
{
    const int t = threadIdx.x;
    const int q = blockIdx.x * 8 + (t >> 5);
    const int quad = t & 31;
    const int s = start[q];
    const int e = start[q + 1];

    float4 acc = make_float4(0.f, 0.f, 0.f, 0.f);
    for (int i = s; i < e; ++i) {
        const float4 v = *(const float4*)&h2[(size_t)i * BOT + quad * 4];
        acc.x += v.x; acc.y += v.y; acc.z += v.z; acc.w += v.w;
    }
    const float inv = 1.0f / (float)((e - s) > 0 ? (e - s) : 1);
    float m0 = acc.x * inv, m1 = acc.y * inv, m2 = acc.z * inv, m3 = acc.w * inv;
    unsigned short h0 = f2bf(m0), h1 = f2bf(m1), h2s = f2bf(m2), h3 = f2bf(m3);
    uint2 H, L;
    H.x = pack2(h0, h1); H.y = pack2(h2s, h3);
    L.x = pack2(f2bf(m0 - bf2f(h0)), f2bf(m1 - bf2f(h1)));
    L.y = pack2(f2bf(m2 - bf2f(h2s)), f2bf(m3 - bf2f(h3)));
    *(uint2*)&mH[(size_t)q * BOT + quad * 4] = H;
    *(uint2*)&mL[(size_t)q * BOT + quad * 4] = L;
}

// ---------------------------------------------------------------------------
// out[NQ,4] = g1[NQ,256] @ pw1[256,4] + pb1 : one wave per row
// ---------------------------------------------------------------------------
__global__ __launch_bounds__(256) void pred1_kernel(
    const float* __restrict__ g1, const float* __restrict__ w,
    const float* __restrict__ b, float* __restrict__ out)
{
    const int wave = threadIdx.x >> 6;
    const int lane = threadIdx.x & 63;
    const int row  = blockIdx.x * 4 + wave;

    const float* g = g1 + (size_t)row * 256;
    float a0 = 0, a1 = 0, a2 = 0, a3 = 0;
    #pragma unroll
    for (int i = 0; i < 4; ++i) {
        int k = lane + 64 * i;
        float gv = g[k];
        const float* wr = w + k * 4;
        a0 = fmaf(gv, wr[0], a0);
        a1 = fmaf(gv, wr[1], a1);
        a2 = fmaf(gv, wr[2], a2);
        a3 = fmaf(gv, wr[3], a3);
    }
    #pragma unroll
    for (int off = 32; off > 0; off >>= 1) {
        a0 += __shfl_down(a0, off, 64);
        a1 += __shfl_down(a1, off, 64);
        a2 += __shfl_down(a2, off, 64);
        a3 += __shfl_down(a3, off, 64);
    }
    if (lane == 0) {
        float4 o = {a0 + b[0], a1 + b[1], a2 + b[2], a3 + b[3]};
        *(float4*)&out[(size_t)row * 4] = o;
    }
}

// ---------------------------------------------------------------------------
extern "C" void kernel_launch(void* const* d_in, const int* in_sizes, int n_in,
                              void* d_out, int out_size, void* d_ws, size_t ws_size,
                              hipStream_t stream)
{
    const float* x    = (const float*)d_in[0];
    const float* qpos = (const float*)d_in[1];
    const int*   edges= (const int*)  d_in[2];
    const float* w0   = (const float*)d_in[3];
    const float* b0   = (const float*)d_in[4];
    const float* w1   = (const float*)d_in[5];
    const float* b1   = (const float*)d_in[6];
    const float* w2   = (const float*)d_in[7];
    const float* b2   = (const float*)d_in[8];
    const float* pw0  = (const float*)d_in[9];
    const float* pb0  = (const float*)d_in[10];
    const float* pw1  = (const float*)d_in[11];
    const float* pb1  = (const float*)d_in[12];
    float* out = (float*)d_out;

    char* ws = (char*)d_ws;
    unsigned short* xH    = (unsigned short*)(ws + OFF_XH);
    unsigned short* xL    = (unsigned short*)(ws + OFF_XL);
    float*          Z     = (float*)(ws + OFF_Z);
    unsigned short* peH   = (unsigned short*)(ws + OFF_PEH);
    unsigned short* peL   = (unsigned short*)(ws + OFF_PEL);
    float*          h2    = (float*)(ws + OFF_H2);
    unsigned short* w0aH  = (unsigned short*)(ws + OFF_W0AH);
    unsigned short* w0aL  = (unsigned short*)(ws + OFF_W0AL);
    unsigned short* w0bH  = (unsigned short*)(ws + OFF_W0BH);
    unsigned short* w0bL  = (unsigned short*)(ws + OFF_W0BL);
    unsigned short* w1H   = (unsigned short*)(ws + OFF_W1H);
    unsigned short* w1L   = (unsigned short*)(ws + OFF_W1L);
    unsigned short* w2H   = (unsigned short*)(ws + OFF_W2H);
    unsigned short* w2L   = (unsigned short*)(ws + OFF_W2L);
    unsigned short* pw0H  = (unsigned short*)(ws + OFF_PW0H);
    unsigned short* pw0L  = (unsigned short*)(ws + OFF_PW0L);
    float*          bconst= (float*)(ws + OFF_BCONST);
    int*            start = (int*)(ws + OFF_START);
    unsigned short* meanH = (unsigned short*)(ws + OFF_MEANH);
    unsigned short* meanL = (unsigned short*)(ws + OFF_MEANL);
    float*          g1    = (float*)(ws + OFF_G1);

    // allow 48 KB dynamic LDS for the fused kernel (once per process)
    static bool attr_done = false;
    if (!attr_done) {
        hipFuncSetAttribute(reinterpret_cast<const void*>(&fused_edge),
                            hipFuncAttributeMaxDynamicSharedMemorySize, 49152);
        attr_done = true;
    }

    // one-time conversions
    conv_x<<<SEQ_/4, 256, 0, stream>>>(x, xH, xL);
    conv_w<<<(IN_DIM*H0_DIM + 255)/256, 256, 0, stream>>>(w0, w0aH, w0aL, IN_DIM, H0_DIM);
    conv_w<<<(PE_K*H0_DIM + 255)/256, 256, 0, stream>>>(w0 + (size_t)IN_DIM*H0_DIM, w0bH, w0bL, PE_K, H0_DIM);
    conv_w<<<(H0_DIM*H1_DIM + 255)/256, 256, 0, stream>>>(w1, w1H, w1L, H0_DIM, H1_DIM);
    conv_w<<<(H1_DIM*BOT + 255)/256, 256, 0, stream>>>(w2, w2H, w2L, H1_DIM, BOT);
    conv_w<<<(BOT*H1_DIM + 255)/256, 256, 0, stream>>>(pw0, pw0H, pw0L, BOT, H1_DIM);
    bias_fold<<<2, 256, 0, stream>>>(w0, b0, bconst);
    seg_offsets<<<(NE_ + 1 + 255)/256, 256, 0, stream>>>(edges, start);

    // Z = PE @ W0b' + bconst for all queries (4 L3-resident PE windows)
    for (int wn = 0; wn < NWIN; ++wn) {
        build_pe<<<QWIN/4, 256, 0, stream>>>(qpos, wn * QWIN, peH, peL);
        gemm_mfma<0, 0, 0><<<dim3(H0_DIM/128, QWIN/128), 256, 0, stream>>>(
            peH, peL, w0bH, w0bL, bconst, Z + (size_t)wn * QWIN * H0_DIM,
            nullptr, nullptr, QWIN, PE_K, H0_DIM, nullptr, nullptr);
    }

    // fused 3-layer edge MLP (64-edge tiles, 2 blocks/CU, rolled K-loops)
    fused_edge<<<NE_/64, 256, 49152, stream>>>(
        xH, xL, w0aH, w0aL, w1H, w1L, w2H, w2L,
        Z, b1, b2, edges, h2);

    seg_mean<<<NQ_/8, 256, 0, stream>>>(start, h2, meanH, meanL);
    gemm_mfma<1, 0, 0><<<dim3(H1_DIM/128, NQ_/128), 256, 0, stream>>>(
        meanH, meanL, pw0H, pw0L, pb0, g1, nullptr, nullptr,
        NQ_, BOT, H1_DIM, nullptr, nullptr);
    pred1_kernel<<<NQ_/4, 256, 0, stream>>>(g1, pw1, pb1, out);
}

// Round 8
// 1699.424 us; speedup vs baseline: 1.4433x; 1.4433x over previous
//
#include <hip/hip_runtime.h>
#include <cmath>

// Problem constants
#define IN_DIM   256
#define H0_DIM   512
#define H1_DIM   256
#define BOT      128
#define NQ_      131072
#define NE_      262144
#define SEQ_     262144
#define QWIN     32768
#define NWIN     (NQ_/QWIN)
#define PE_K     384          // PE cols 384..511 are constant -> folded into bias

// Workspace layout (bytes), ws = 1 GiB.
static const size_t OFF_XH    = 0;            // 262144*256*2 = 134217728
static const size_t OFF_XL    = 134217728;
static const size_t OFF_Z     = 268435456;    // 131072*512*4 = 268435456
static const size_t OFF_PEH   = 536870912;    // 32768*384*2 = 25165824
static const size_t OFF_PEL   = 562036736;
static const size_t OFF_H2    = 738197504;    // 262144*128*4 = 134217728
static const size_t OFF_W0AH  = 872415232;    // [512][256] 262144
static const size_t OFF_W0AL  = 872677376;
static const size_t OFF_W0BH  = 872939520;    // [512][384] 393216
static const size_t OFF_W0BL  = 873332736;
static const size_t OFF_W1H   = 873725952;    // [256][512] 262144
static const size_t OFF_W1L   = 873988096;
static const size_t OFF_W2H   = 874250240;    // [128][256] 65536
static const size_t OFF_W2L   = 874315776;
static const size_t OFF_PW0H  = 874381312;    // [256][128] 65536
static const size_t OFF_PW0L  = 874446848;
static const size_t OFF_BCONST= 874512384;    // 512*4
static const size_t OFF_START = 874514432;    // (NQ+1)*4
// post-loop aliases
static const size_t OFF_MEANH = 0;            // alias xH (dead after fused edge kernel)
static const size_t OFF_MEANL = 33554432;
static const size_t OFF_G1    = 268435456;    // alias Z (dead after fused edge kernel)

typedef __attribute__((ext_vector_type(8))) short bf16x8;
typedef __attribute__((ext_vector_type(4))) float f32x4;

__device__ __forceinline__ float gelu_f(float v) {
    return v * 0.5f * (1.0f + erff(v * 0.7071067811865476f));
}
__device__ __forceinline__ unsigned short f2bf(float f) {
    unsigned int u = __float_as_uint(f);
    unsigned int r = (u + 0x7FFFu + ((u >> 16) & 1u)) >> 16;
    return (unsigned short)r;
}
__device__ __forceinline__ float bf2f(unsigned short h) {
    return __uint_as_float(((unsigned int)h) << 16);
}
__device__ __forceinline__ unsigned int pack2(unsigned short a, unsigned short b) {
    return (unsigned int)a | ((unsigned int)b << 16);
}
__device__ __forceinline__ void stage16(const void* g, void* l) {
    __builtin_amdgcn_global_load_lds(
        (const __attribute__((address_space(1))) unsigned int*)g,
        (__attribute__((address_space(3))) unsigned int*)l,
        16, 0, 0);
}
// float4 -> 2x(hi pair) + 2x(lo pair)
__device__ __forceinline__ void cvt4(const float4 v, unsigned int* hw, unsigned int* lw) {
    const unsigned short a = f2bf(v.x), b = f2bf(v.y), c = f2bf(v.z), d = f2bf(v.w);
    hw[0] = pack2(a, b); hw[1] = pack2(c, d);
    lw[0] = pack2(f2bf(v.x - bf2f(a)), f2bf(v.y - bf2f(b)));
    lw[1] = pack2(f2bf(v.z - bf2f(c)), f2bf(v.w - bf2f(d)));
}

// ---------------------------------------------------------------------------
// x fp32 [SEQ][256] -> xH/xL bf16 (wave per row)
// ---------------------------------------------------------------------------
__global__ __launch_bounds__(256) void conv_x(
    const float* __restrict__ x,
    unsigned short* __restrict__ xH, unsigned short* __restrict__ xL)
{
    const int wv = threadIdx.x >> 6;
    const int l  = threadIdx.x & 63;
    const int row = blockIdx.x * 4 + wv;
    const size_t base = (size_t)row * IN_DIM + l * 4;
    float4 v = *(const float4*)&x[base];
    unsigned short h0 = f2bf(v.x), h1 = f2bf(v.y), h2 = f2bf(v.z), h3 = f2bf(v.w);
    uint2 H, L;
    H.x = pack2(h0, h1); H.y = pack2(h2, h3);
    L.x = pack2(f2bf(v.x - bf2f(h0)), f2bf(v.y - bf2f(h1)));
    L.y = pack2(f2bf(v.z - bf2f(h2)), f2bf(v.w - bf2f(h3)));
    *(uint2*)&xH[base] = H;
    *(uint2*)&xL[base] = L;
}

// ---------------------------------------------------------------------------
// Weight convert: W[K][N] fp32 -> WT hi/lo bf16 [N][K]
// ---------------------------------------------------------------------------
__global__ __launch_bounds__(256) void conv_w(
    const float* __restrict__ W, unsigned short* __restrict__ WTh,
    unsigned short* __restrict__ WTl, int K, int N)
{
    int idx = blockIdx.x * 256 + threadIdx.x;
    if (idx >= K * N) return;
    int k = idx / N, n = idx % N;
    float v = W[idx];
    unsigned short h = f2bf(v);
    WTh[(size_t)n * K + k] = h;
    WTl[(size_t)n * K + k] = f2bf(v - bf2f(h));
}

// ---------------------------------------------------------------------------
// bconst[n] = b0[n] + sum_j sin(om_j)*w0[640+j][n] + cos(om_j)*w0[704+j][n]
// ---------------------------------------------------------------------------
__global__ __launch_bounds__(256) void bias_fold(
    const float* __restrict__ w0, const float* __restrict__ b0,
    float* __restrict__ bconst)
{
    int n = blockIdx.x * 256 + threadIdx.x;
    if (n >= H0_DIM) return;
    float s = b0[n];
    for (int j = 0; j < 64; ++j) {
        float om = exp2f((float)j * (-13.287712379549449f / 64.0f));
        s += sinf(om) * w0[(size_t)(640 + j) * H0_DIM + n];
        s += cosf(om) * w0[(size_t)(704 + j) * H0_DIM + n];
    }
    bconst[n] = s;
}

// ---------------------------------------------------------------------------
// start[q] = first edge index with qidx >= q (qidx sorted ascending)
// ---------------------------------------------------------------------------
__global__ __launch_bounds__(256) void seg_offsets(
    const int* __restrict__ edges, int* __restrict__ start)
{
    int e = blockIdx.x * 256 + threadIdx.x;
    if (e > NE_) return;
    int qc = (e < NE_) ? edges[2 * e] : NQ_;
    int qp = (e > 0) ? edges[2 * e - 2] : -1;
    for (int q = qp + 1; q <= qc; ++q) start[q] = e;
}

// ---------------------------------------------------------------------------
// PE build for window: rows i in [0,QWIN), query q = qbase+i, cols 0..383.
// ---------------------------------------------------------------------------
__global__ __launch_bounds__(256) void build_pe(
    const float* __restrict__ qpos, int qbase,
    unsigned short* __restrict__ peH, unsigned short* __restrict__ peL)
{
    const int wv = threadIdx.x >> 6;
    const int l  = threadIdx.x & 63;
    const int i  = blockIdx.x * 4 + wv;
    const int i0 = l * 8;
    if (i0 >= PE_K) return;
    const int q  = qbase + i;
    const size_t base = (size_t)i * PE_K;

    const int cc = i0 >> 7;          // coord 0..2
    const int j0 = i0 & 127;
    const float cv = qpos[q * 3 + cc] * 0.01f - 1.0f;
    const bool is_sin = (j0 < 64);
    const int jj0 = j0 & 63;
    unsigned int hw[4], lw[4];
    #pragma unroll
    for (int p2 = 0; p2 < 4; ++p2) {
        unsigned short hh[2], ll[2];
        #pragma unroll
        for (int s = 0; s < 2; ++s) {
            int jj = jj0 + p2 * 2 + s;
            float om  = exp2f((float)jj * (-13.287712379549449f / 64.0f));
            float arg = cv * om;
            float v   = is_sin ? __sinf(arg) : __cosf(arg);
            unsigned short h = f2bf(v);
            hh[s] = h; ll[s] = f2bf(v - bf2f(h));
        }
        hw[p2] = pack2(hh[0], hh[1]);
        lw[p2] = pack2(ll[0], ll[1]);
    }
    uint4 H, L;
    H.x = hw[0]; H.y = hw[1]; H.z = hw[2]; H.w = hw[3];
    L.x = lw[0]; L.y = lw[1]; L.z = lw[2]; L.w = lw[3];
    *(uint4*)&peH[base + i0] = H;
    *(uint4*)&peL[base + i0] = L;
}

// ---------------------------------------------------------------------------
// Split-bf16 MFMA GEMM (3 passes AhBh+AhBl+AlBh). 128x128 tile, BK=32.
// R2's proven structure: A and B both LDS-staged (8x stage16/step), 2-barrier
// K-loop. Used for the Z build (PE @ W0b') and the pred0 GEMM.
// ---------------------------------------------------------------------------
template <int ACT, int OUT_MODE, int GATHER>
__global__ __launch_bounds__(256) void gemm_mfma(
    const unsigned short* __restrict__ Ah, const unsigned short* __restrict__ Al,
    const unsigned short* __restrict__ Bh, const unsigned short* __restrict__ Bl,
    const float* __restrict__ bias,
    float* __restrict__ Cf, unsigned short* __restrict__ ChO, unsigned short* __restrict__ ClO,
    int M, int K, int N,
    const int* __restrict__ gp, const float* __restrict__ Zw)
{
    __shared__ __align__(16) short lds[4][128][32];   // 32 KB

    const int tid = threadIdx.x;
    const int w   = tid >> 6;
    const int l   = tid & 63;
    const int l16 = l & 15;
    const int lq  = l >> 4;
    const int bm  = blockIdx.y * 128;
    const int bn  = blockIdx.x * 128;
    const int wm  = (w & 1) * 64;
    const int wn  = (w >> 1) * 64;

    f32x4 acc[4][4];
    #pragma unroll
    for (int i = 0; i < 4; ++i)
        #pragma unroll
        for (int j = 0; j < 4; ++j)
            acc[i][j] = (f32x4){0.f, 0.f, 0.f, 0.f};

    const int jrow = l >> 2;
    const int jkc  = l & 3;
    const int t0 = w * 2, t1 = t0 + 1;
    const int r0 = t0 * 16 + jrow, r1 = t1 * 16 + jrow;

    size_t arow0, arow1;
    if (GATHER) {
        arow0 = (size_t)gp[2 * (bm + r0) + 1] * K;
        arow1 = (size_t)gp[2 * (bm + r1) + 1] * K;
    } else {
        arow0 = (size_t)(bm + r0) * K;
        arow1 = (size_t)(bm + r1) * K;
    }
    const size_t brow0 = (size_t)(bn + r0) * K;
    const size_t brow1 = (size_t)(bn + r1) * K;
    short* d00 = &lds[0][0][0] + t0 * 512;
    short* d01 = &lds[1][0][0] + t0 * 512;
    short* d02 = &lds[2][0][0] + t0 * 512;
    short* d03 = &lds[3][0][0] + t0 * 512;
    short* d10 = &lds[0][0][0] + t1 * 512;
    short* d11 = &lds[1][0][0] + t1 * 512;
    short* d12 = &lds[2][0][0] + t1 * 512;
    short* d13 = &lds[3][0][0] + t1 * 512;

    for (int k0 = 0; k0 < K; k0 += 32) {
        const int ko = k0 + jkc * 8;
        stage16(Ah + arow0 + ko, d00);
        stage16(Al + arow0 + ko, d01);
        stage16(Bh + brow0 + ko, d02);
        stage16(Bl + brow0 + ko, d03);
        stage16(Ah + arow1 + ko, d10);
        stage16(Al + arow1 + ko, d11);
        stage16(Bh + brow1 + ko, d12);
        stage16(Bl + brow1 + ko, d13);
        __syncthreads();

        bf16x8 ah[4], al[4], bh[4], bl[4];
        #pragma unroll
        for (int i = 0; i < 4; ++i) {
            ah[i] = *(const bf16x8*)&lds[0][wm + i*16 + l16][lq*8];
            al[i] = *(const bf16x8*)&lds[1][wm + i*16 + l16][lq*8];
            bh[i] = *(const bf16x8*)&lds[2][wn + i*16 + l16][lq*8];
            bl[i] = *(const bf16x8*)&lds[3][wn + i*16 + l16][lq*8];
        }
        #pragma unroll
        for (int i = 0; i < 4; ++i)
            #pragma unroll
            for (int j = 0; j < 4; ++j) {
                acc[i][j] = __builtin_amdgcn_mfma_f32_16x16x32_bf16(ah[i], bh[j], acc[i][j], 0, 0, 0);
                acc[i][j] = __builtin_amdgcn_mfma_f32_16x16x32_bf16(ah[i], bl[j], acc[i][j], 0, 0, 0);
                acc[i][j] = __builtin_amdgcn_mfma_f32_16x16x32_bf16(al[i], bh[j], acc[i][j], 0, 0, 0);
            }
        __syncthreads();
    }

    if (OUT_MODE == 0) {
        #pragma unroll
        for (int j = 0; j < 4; ++j) {
            int n = bn + wn + j * 16 + l16;
            float bv = bias[n];
            #pragma unroll
            for (int i = 0; i < 4; ++i) {
                int mrow = bm + wm + i * 16 + lq * 4;
                #pragma unroll
                for (int r = 0; r < 4; ++r) {
                    float v = acc[i][j][r] + bv;
                    if (ACT) v = gelu_f(v);
                    Cf[(size_t)(mrow + r) * N + n] = v;
                }
            }
        }
    }
}

// ---------------------------------------------------------------------------
// FUSED edge MLP, v8: R6/R7 structure with BOTH spill mechanisms closed.
//  (a) K-loops (ks, ks2) forced ROLLED (#pragma unroll 1): auto-unroll
//      hoisted 4 iterations of global B-fragment loads -> 128 extra live
//      VGPRs -> R6's 245 MB scratch.
//  (b) Accumulator-indexing loops (epilogue jj, h2-transpose jj) forced
//      UNROLLED: R7 rolled them, making acc1[i][jj]/h1acc[i][jj]
//      runtime-indexed -> whole arrays demoted to scratch (rule #20) ->
//      R7's 4.1 GB scratch.
// Structure unchanged otherwise: only gathered x staged in LDS; W0a/W1/W2
// fragments global->VGPR (L2-hot); h1/h2 K-loops barrier-free.
// LDS 48 KB: stage/lbuf 16 KB + h0h 16 KB + h0l 16 KB. (256,2): no spill cap.
// ---------------------------------------------------------------------------
__global__ __launch_bounds__(256, 2) void fused_edge(
    const unsigned short* __restrict__ xHg, const unsigned short* __restrict__ xLg,
    const unsigned short* __restrict__ w0aHg, const unsigned short* __restrict__ w0aLg,
    const unsigned short* __restrict__ w1Hg, const unsigned short* __restrict__ w1Lg,
    const unsigned short* __restrict__ w2Hg, const unsigned short* __restrict__ w2Lg,
    const float* __restrict__ Zg, const float* __restrict__ b1g,
    const float* __restrict__ b2g, const int* __restrict__ gp,
    float* __restrict__ h2g)
{
    extern __shared__ __align__(16) short smem[];
    // region [0, 8192): A stage [64][32] hi@0 lo@2048 (8 KB) / lbuf alias (16 KB)
    short* h0h = smem + 8192;    // [64][128] = 16 KB
    short* h0l = smem + 16384;   // 16 KB

    const int tid = threadIdx.x;
    const int w   = tid >> 6;
    const int l   = tid & 63;
    const int l16 = l & 15;
    const int lq  = l >> 4;
    const int bm  = blockIdx.x * 64;

    const int wn_p = w * 32;   // phase-1 / h2 col base
    const int wn1  = w * 64;   // h1 col base (0..255)

    // A staging: thread covers row rx = tid>>2, 16B unit ux = tid&3
    const int rx = tid >> 2;
    const int ux = tid & 3;
    const unsigned int xoff = (unsigned)gp[2 * (bm + rx) + 1] * 256u + ux * 8;
    const int q_e = gp[2 * (bm + l)];
    const unsigned int zq = (unsigned)q_e * 512u;
    float* lbuf = ((float*)smem) + w * 1024;   // per-wave [64][16] f32

    f32x4 h1acc[4][4];
    #pragma unroll
    for (int i = 0; i < 4; ++i)
        #pragma unroll
        for (int j = 0; j < 4; ++j)
            h1acc[i][j] = (f32x4){0.f, 0.f, 0.f, 0.f};

    const int rsw7 = l16 & 7;   // (row & 7) for fragment rows i*16+l16

    #pragma unroll 1
    for (int c = 0; c < 4; ++c) {
        f32x4 acc1[4][2];
        #pragma unroll
        for (int i = 0; i < 4; ++i)
            #pragma unroll
            for (int j = 0; j < 2; ++j)
                acc1[i][j] = (f32x4){0.f, 0.f, 0.f, 0.f};

        // ---- phase 1: h0c[64][128] = x[gidx] @ W0a_c, K=256 ----
        stage16(xHg + xoff, smem + tid * 8);
        stage16(xLg + xoff, smem + 2048 + tid * 8);
        __syncthreads();
        #pragma unroll 1
        for (int ks = 0; ks < 8; ++ks) {
            bf16x8 a_h[4], a_l[4], b_h[2], b_l[2];
            #pragma unroll
            for (int i = 0; i < 4; ++i) {
                const int ro = (i * 16 + l16) * 32 + lq * 8;
                a_h[i] = *(const bf16x8*)&smem[ro];
                a_l[i] = *(const bf16x8*)&smem[2048 + ro];
            }
            {
                const unsigned kk = (unsigned)(ks * 32 + lq * 8);
                #pragma unroll
                for (int j = 0; j < 2; ++j) {
                    const unsigned n = (unsigned)(c * 128 + wn_p + j * 16 + l16);
                    b_h[j] = *(const bf16x8*)&w0aHg[n * 256u + kk];
                    b_l[j] = *(const bf16x8*)&w0aLg[n * 256u + kk];
                }
            }
            __syncthreads();    // stage-region reads done
            if (ks < 7) {
                const int ko = (ks + 1) * 32;
                stage16(xHg + xoff + ko, smem + tid * 8);
                stage16(xLg + xoff + ko, smem + 2048 + tid * 8);
            }
            #pragma unroll
            for (int i = 0; i < 4; ++i)
                #pragma unroll
                for (int j = 0; j < 2; ++j) {
                    acc1[i][j] = __builtin_amdgcn_mfma_f32_16x16x32_bf16(a_h[i], b_h[j], acc1[i][j], 0, 0, 0);
                    acc1[i][j] = __builtin_amdgcn_mfma_f32_16x16x32_bf16(a_h[i], b_l[j], acc1[i][j], 0, 0, 0);
                    acc1[i][j] = __builtin_amdgcn_mfma_f32_16x16x32_bf16(a_l[i], b_h[j], acc1[i][j], 0, 0, 0);
                }
            __syncthreads();    // stage visible
        }

        // ---- epilogue: +Z, gelu, cvt -> h0h/h0l (per-wave lbuf) ----
        // UNROLLED so acc1[i][jj] is compile-time-indexed (rule #20).
        #pragma unroll
        for (int jj = 0; jj < 2; ++jj) {
            #pragma unroll
            for (int i = 0; i < 4; ++i)
                #pragma unroll
                for (int r = 0; r < 4; ++r) {
                    const int rowq = i * 16 + lq * 4 + r;
                    const int u = l16 >> 2;
                    lbuf[rowq * 16 + (((u ^ ((rowq >> 1) & 3)) << 2) | (l16 & 3))] = acc1[i][jj][r];
                }
            const unsigned zc = zq + (unsigned)(c * 128 + wn_p + jj * 16);
            unsigned int hw[8], lw[8];
            #pragma unroll
            for (int i4 = 0; i4 < 4; ++i4) {
                float4 v = *(const float4*)&lbuf[l * 16 + ((i4 ^ ((l >> 1) & 3)) << 2)];
                const float4 z = *(const float4*)&Zg[zc + i4 * 4];
                v.x = gelu_f(v.x + z.x); v.y = gelu_f(v.y + z.y);
                v.z = gelu_f(v.z + z.z); v.w = gelu_f(v.w + z.w);
                cvt4(v, &hw[i4 * 2], &lw[i4 * 2]);
            }
            const int cu0 = w * 4 + jj * 2;
            const int o0 = l * 128 + (((cu0    ) ^ (l & 7)) << 3);
            const int o1 = l * 128 + (((cu0 + 1) ^ (l & 7)) << 3);
            uint4 H0, H1, L0, L1;
            H0.x = hw[0]; H0.y = hw[1]; H0.z = hw[2]; H0.w = hw[3];
            H1.x = hw[4]; H1.y = hw[5]; H1.z = hw[6]; H1.w = hw[7];
            L0.x = lw[0]; L0.y = lw[1]; L0.z = lw[2]; L0.w = lw[3];
            L1.x = lw[4]; L1.y = lw[5]; L1.z = lw[6]; L1.w = lw[7];
            *(uint4*)&h0h[o0] = H0; *(uint4*)&h0h[o1] = H1;
            *(uint4*)&h0l[o0] = L0; *(uint4*)&h0l[o1] = L1;
        }
        __syncthreads();   // h0 sub-tile visible to all waves

        // ---- h1 partial: h1acc += h0c @ W1[c*128.., :], K=128, NO barriers ----
        // ROLLED: auto-unroll hoists 4 iterations of B global loads -> spill.
        // h1acc indices inside are compile-time (i,j unrolled) -> stays in regs.
        #pragma unroll 1
        for (int ks2 = 0; ks2 < 4; ++ks2) {
            bf16x8 a_h[4], a_l[4], b_h[4], b_l[4];
            #pragma unroll
            for (int i = 0; i < 4; ++i) {
                const int ro = (i * 16 + l16) * 128 + (((ks2 * 4 + lq) ^ rsw7) << 3);
                a_h[i] = *(const bf16x8*)&h0h[ro];
                a_l[i] = *(const bf16x8*)&h0l[ro];
            }
            {
                const unsigned kk = (unsigned)(c * 128 + ks2 * 32 + lq * 8);
                #pragma unroll
                for (int j = 0; j < 4; ++j) {
                    const unsigned n = (unsigned)(wn1 + j * 16 + l16);
                    b_h[j] = *(const bf16x8*)&w1Hg[n * 512u + kk];
                    b_l[j] = *(const bf16x8*)&w1Lg[n * 512u + kk];
                }
            }
            #pragma unroll
            for (int i = 0; i < 4; ++i)
                #pragma unroll
                for (int j = 0; j < 4; ++j) {
                    h1acc[i][j] = __builtin_amdgcn_mfma_f32_16x16x32_bf16(a_h[i], b_h[j], h1acc[i][j], 0, 0, 0);
                    h1acc[i][j] = __builtin_amdgcn_mfma_f32_16x16x32_bf16(a_h[i], b_l[j], h1acc[i][j], 0, 0, 0);
                    h1acc[i][j] = __builtin_amdgcn_mfma_f32_16x16x32_bf16(a_l[i], b_h[j], h1acc[i][j], 0, 0, 0);
                }
        }
        // next c's staging happens after this loop; lbuf readers were
        // pre-barrier, so the alias is safe.
    }

    // ---- h2 = gelu(h1 + b1) @ W2 + b2, K=256 in two 128-col halves ----
    f32x4 acc2[4][2];
    #pragma unroll
    for (int i = 0; i < 4; ++i)
        #pragma unroll
        for (int j = 0; j < 2; ++j)
            acc2[i][j] = (f32x4){0.f, 0.f, 0.f, 0.f};

    #pragma unroll 1
    for (int kh = 0; kh < 2; ++kh) {
        const bool my = ((w >> 1) == kh);   // wave w owns h1 cols w*64..w*64+63
        __syncthreads();   // previous readers of h0 bufs done
        if (my) {
            // UNROLLED so h1acc[i][jj] is compile-time-indexed (rule #20).
            #pragma unroll
            for (int jj = 0; jj < 4; ++jj) {
                const float bv = b1g[wn1 + jj * 16 + l16];
                #pragma unroll
                for (int i = 0; i < 4; ++i)
                    #pragma unroll
                    for (int r = 0; r < 4; ++r) {
                        const int rowq = i * 16 + lq * 4 + r;
                        const int u = l16 >> 2;
                        lbuf[rowq * 16 + (((u ^ ((rowq >> 1) & 3)) << 2) | (l16 & 3))] =
                            gelu_f(h1acc[i][jj][r] + bv);
                    }
                unsigned int hw[8], lw[8];
                #pragma unroll
                for (int i4 = 0; i4 < 4; ++i4) {
                    float4 v = *(const float4*)&lbuf[l * 16 + ((i4 ^ ((l >> 1) & 3)) << 2)];
                    cvt4(v, &hw[i4 * 2], &lw[i4 * 2]);
                }
                const int cu0 = (w & 1) * 8 + jj * 2;
                const int o0 = l * 128 + (((cu0    ) ^ (l & 7)) << 3);
                const int o1 = l * 128 + (((cu0 + 1) ^ (l & 7)) << 3);
                uint4 H0, H1, L0, L1;
                H0.x = hw[0]; H0.y = hw[1]; H0.z = hw[2]; H0.w = hw[3];
                H1.x = hw[4]; H1.y = hw[5]; H1.z = hw[6]; H1.w = hw[7];
                L0.x = lw[0]; L0.y = lw[1]; L0.z = lw[2]; L0.w = lw[3];
                L1.x = lw[4]; L1.y = lw[5]; L1.z = lw[6]; L1.w = lw[7];
                *(uint4*)&h0h[o0] = H0; *(uint4*)&h0h[o1] = H1;
                *(uint4*)&h0l[o0] = L0; *(uint4*)&h0l[o1] = L1;
            }
        }
        __syncthreads();   // h1 half visible

        // ROLLED (same B-load-hoist reason as the h1 loop); acc2 indices static.
        #pragma unroll 1
        for (int ks2 = 0; ks2 < 4; ++ks2) {
            bf16x8 a_h[4], a_l[4], b_h[2], b_l[2];
            #pragma unroll
            for (int i = 0; i < 4; ++i) {
                const int ro = (i * 16 + l16) * 128 + (((ks2 * 4 + lq) ^ rsw7) << 3);
                a_h[i] = *(const bf16x8*)&h0h[ro];
                a_l[i] = *(const bf16x8*)&h0l[ro];
            }
            {
                const unsigned kk = (unsigned)(kh * 128 + ks2 * 32 + lq * 8);
                #pragma unroll
                for (int j = 0; j < 2; ++j) {
                    const unsigned n = (unsigned)(wn_p + j * 16 + l16);
                    b_h[j] = *(const bf16x8*)&w2Hg[n * 256u + kk];
                    b_l[j] = *(const bf16x8*)&w2Lg[n * 256u + kk];
                }
            }
            #pragma unroll
            for (int i = 0; i < 4; ++i)
                #pragma unroll
                for (int j = 0; j < 2; ++j) {
                    acc2[i][j] = __builtin_amdgcn_mfma_f32_16x16x32_bf16(a_h[i], b_h[j], acc2[i][j], 0, 0, 0);
                    acc2[i][j] = __builtin_amdgcn_mfma_f32_16x16x32_bf16(a_h[i], b_l[j], acc2[i][j], 0, 0, 0);
                    acc2[i][j] = __builtin_amdgcn_mfma_f32_16x16x32_bf16(a_l[i], b_h[j], acc2[i][j], 0, 0, 0);
                }
        }
    }

    // ---- h2 epilogue: + b2, fp32 store ----
    #pragma unroll
    for (int j = 0; j < 2; ++j) {
        const int n = wn_p + j * 16 + l16;
        const float bv = b2g[n];
        #pragma unroll
        for (int i = 0; i < 4; ++i) {
            const int er = bm + i * 16 + lq * 4;
            #pragma unroll
            for (int r = 0; r < 4; ++r)
                h2g[(size_t)(er + r) * BOT + n] = acc2[i][j][r] + bv;
        }
    }
}

// ---------------------------------------------------------------------------
// segment mean via precomputed offsets
// ---------------------------------------------------------------------------
__global__ __launch_bounds__(256) void seg_mean(
    const int* __restrict__ start, const float* __restrict__ h2,
    unsigned short* __restrict__ mH, unsigned short* __restrict__ mL)
{
    const int t = threadIdx.x;
    const int q = blockIdx.x * 8 + (t >> 5);
    const int quad = t & 31;
    const int s = start[q];
    const int e = start[q + 1];

    float4 acc = make_float4(0.f, 0.f, 0.f, 0.f);
    for (int i = s; i < e; ++i) {
        const float4 v = *(const float4*)&h2[(size_t)i * BOT + quad * 4];
        acc.x += v.x; acc.y += v.y; acc.z += v.z; acc.w += v.w;
    }
    const float inv = 1.0f / (float)((e - s) > 0 ? (e - s) : 1);
    float m0 = acc.x * inv, m1 = acc.y * inv, m2 = acc.z * inv, m3 = acc.w * inv;
    unsigned short h0 = f2bf(m0), h1 = f2bf(m1), h2s = f2bf(m2), h3 = f2bf(m3);
    uint2 H, L;
    H.x = pack2(h0, h1); H.y = pack2(h2s, h3);
    L.x = pack2(f2bf(m0 - bf2f(h0)), f2bf(m1 - bf2f(h1)));
    L.y = pack2(f2bf(m2 - bf2f(h2s)), f2bf(m3 - bf2f(h3)));
    *(uint2*)&mH[(size_t)q * BOT + quad * 4] = H;
    *(uint2*)&mL[(size_t)q * BOT + quad * 4] = L;
}

// ---------------------------------------------------------------------------
// out[NQ,4] = g1[NQ,256] @ pw1[256,4] + pb1 : one wave per row
// ---------------------------------------------------------------------------
__global__ __launch_bounds__(256) void pred1_kernel(
    const float* __restrict__ g1, const float* __restrict__ w,
    const float* __restrict__ b, float* __restrict__ out)
{
    const int wave = threadIdx.x >> 6;
    const int lane = threadIdx.x & 63;
    const int row  = blockIdx.x * 4 + wave;

    const float* g = g1 + (size_t)row * 256;
    float a0 = 0, a1 = 0, a2 = 0, a3 = 0;
    #pragma unroll
    for (int i = 0; i < 4; ++i) {
        int k = lane + 64 * i;
        float gv = g[k];
        const float* wr = w + k * 4;
        a0 = fmaf(gv, wr[0], a0);
        a1 = fmaf(gv, wr[1], a1);
        a2 = fmaf(gv, wr[2], a2);
        a3 = fmaf(gv, wr[3], a3);
    }
    #pragma unroll
    for (int off = 32; off > 0; off >>= 1) {
        a0 += __shfl_down(a0, off, 64);
        a1 += __shfl_down(a1, off, 64);
        a2 += __shfl_down(a2, off, 64);
        a3 += __shfl_down(a3, off, 64);
    }
    if (lane == 0) {
        float4 o = {a0 + b[0], a1 + b[1], a2 + b[2], a3 + b[3]};
        *(float4*)&out[(size_t)row * 4] = o;
    }
}

// ---------------------------------------------------------------------------
extern "C" void kernel_launch(void* const* d_in, const int* in_sizes, int n_in,
                              void* d_out, int out_size, void* d_ws, size_t ws_size,
                              hipStream_t stream)
{
    const float* x    = (const float*)d_in[0];
    const float* qpos = (const float*)d_in[1];
    const int*   edges= (const int*)  d_in[2];
    const float* w0   = (const float*)d_in[3];
    const float* b0   = (const float*)d_in[4];
    const float* w1   = (const float*)d_in[5];
    const float* b1   = (const float*)d_in[6];
    const float* w2   = (const float*)d_in[7];
    const float* b2   = (const float*)d_in[8];
    const float* pw0  = (const float*)d_in[9];
    const float* pb0  = (const float*)d_in[10];
    const float* pw1  = (const float*)d_in[11];
    const float* pb1  = (const float*)d_in[12];
    float* out = (float*)d_out;

    char* ws = (char*)d_ws;
    unsigned short* xH    = (unsigned short*)(ws + OFF_XH);
    unsigned short* xL    = (unsigned short*)(ws + OFF_XL);
    float*          Z     = (float*)(ws + OFF_Z);
    unsigned short* peH   = (unsigned short*)(ws + OFF_PEH);
    unsigned short* peL   = (unsigned short*)(ws + OFF_PEL);
    float*          h2    = (float*)(ws + OFF_H2);
    unsigned short* w0aH  = (unsigned short*)(ws + OFF_W0AH);
    unsigned short* w0aL  = (unsigned short*)(ws + OFF_W0AL);
    unsigned short* w0bH  = (unsigned short*)(ws + OFF_W0BH);
    unsigned short* w0bL  = (unsigned short*)(ws + OFF_W0BL);
    unsigned short* w1H   = (unsigned short*)(ws + OFF_W1H);
    unsigned short* w1L   = (unsigned short*)(ws + OFF_W1L);
    unsigned short* w2H   = (unsigned short*)(ws + OFF_W2H);
    unsigned short* w2L   = (unsigned short*)(ws + OFF_W2L);
    unsigned short* pw0H  = (unsigned short*)(ws + OFF_PW0H);
    unsigned short* pw0L  = (unsigned short*)(ws + OFF_PW0L);
    float*          bconst= (float*)(ws + OFF_BCONST);
    int*            start = (int*)(ws + OFF_START);
    unsigned short* meanH = (unsigned short*)(ws + OFF_MEANH);
    unsigned short* meanL = (unsigned short*)(ws + OFF_MEANL);
    float*          g1    = (float*)(ws + OFF_G1);

    // allow 48 KB dynamic LDS for the fused kernel (once per process)
    static bool attr_done = false;
    if (!attr_done) {
        hipFuncSetAttribute(reinterpret_cast<const void*>(&fused_edge),
                            hipFuncAttributeMaxDynamicSharedMemorySize, 49152);
        attr_done = true;
    }

    // one-time conversions
    conv_x<<<SEQ_/4, 256, 0, stream>>>(x, xH, xL);
    conv_w<<<(IN_DIM*H0_DIM + 255)/256, 256, 0, stream>>>(w0, w0aH, w0aL, IN_DIM, H0_DIM);
    conv_w<<<(PE_K*H0_DIM + 255)/256, 256, 0, stream>>>(w0 + (size_t)IN_DIM*H0_DIM, w0bH, w0bL, PE_K, H0_DIM);
    conv_w<<<(H0_DIM*H1_DIM + 255)/256, 256, 0, stream>>>(w1, w1H, w1L, H0_DIM, H1_DIM);
    conv_w<<<(H1_DIM*BOT + 255)/256, 256, 0, stream>>>(w2, w2H, w2L, H1_DIM, BOT);
    conv_w<<<(BOT*H1_DIM + 255)/256, 256, 0, stream>>>(pw0, pw0H, pw0L, BOT, H1_DIM);
    bias_fold<<<2, 256, 0, stream>>>(w0, b0, bconst);
    seg_offsets<<<(NE_ + 1 + 255)/256, 256, 0, stream>>>(edges, start);

    // Z = PE @ W0b' + bconst for all queries (4 L3-resident PE windows)
    for (int wn = 0; wn < NWIN; ++wn) {
        build_pe<<<QWIN/4, 256, 0, stream>>>(qpos, wn * QWIN, peH, peL);
        gemm_mfma<0, 0, 0><<<dim3(H0_DIM/128, QWIN/128), 256, 0, stream>>>(
            peH, peL, w0bH, w0bL, bconst, Z + (size_t)wn * QWIN * H0_DIM,
            nullptr, nullptr, QWIN, PE_K, H0_DIM, nullptr, nullptr);
    }

    // fused 3-layer edge MLP (64-edge tiles, 2 blocks/CU, rolled K-loops,
    // static accumulator indexing)
    fused_edge<<<NE_/64, 256, 49152, stream>>>(
        xH, xL, w0aH, w0aL, w1H, w1L, w2H, w2L,
        Z, b1, b2, edges, h2);

    seg_mean<<<NQ_/8, 256, 0, stream>>>(start, h2, meanH, meanL);
    gemm_mfma<1, 0, 0><<<dim3(H1_DIM/128, NQ_/128), 256, 0, stream>>>(
        meanH, meanL, pw0H, pw0L, pb0, g1, nullptr, nullptr,
        NQ_, BOT, H1_DIM, nullptr, nullptr);
    pred1_kernel<<<NQ_/4, 256, 0, stream>>>(g1, pw1, pb1, out);
}

// Round 9
// 1619.267 us; speedup vs baseline: 1.5148x; 1.0495x over previous
//
#include <hip/hip_runtime.h>
#include <cmath>

// Problem constants
#define IN_DIM   256
#define H0_DIM   512
#define H1_DIM   256
#define BOT      128
#define NQ_      131072
#define NE_      262144
#define SEQ_     262144
#define QWIN     32768
#define NWIN     (NQ_/QWIN)
#define PE_K     384          // PE cols 384..511 are constant -> folded into bias

// Workspace layout (bytes), ws = 1 GiB.
static const size_t OFF_XH    = 0;            // 262144*256*2 = 134217728
static const size_t OFF_XL    = 134217728;
static const size_t OFF_Z     = 268435456;    // 131072*512*4 = 268435456
static const size_t OFF_PEH   = 536870912;    // 32768*384*2 = 25165824
static const size_t OFF_PEL   = 562036736;
static const size_t OFF_H2    = 738197504;    // 262144*128*4 = 134217728
static const size_t OFF_W0AH  = 872415232;    // [512][256] 262144
static const size_t OFF_W0AL  = 872677376;
static const size_t OFF_W0BH  = 872939520;    // [512][384] 393216
static const size_t OFF_W0BL  = 873332736;
static const size_t OFF_W1H   = 873725952;    // [256][512] 262144
static const size_t OFF_W1L   = 873988096;
static const size_t OFF_W2H   = 874250240;    // [128][256] 65536
static const size_t OFF_W2L   = 874315776;
static const size_t OFF_PW0H  = 874381312;    // [256][128] 65536
static const size_t OFF_PW0L  = 874446848;
static const size_t OFF_BCONST= 874512384;    // 512*4
static const size_t OFF_START = 874514432;    // (NQ+1)*4
// post-loop aliases
static const size_t OFF_MEANH = 0;            // alias xH (dead after fused edge kernel)
static const size_t OFF_MEANL = 33554432;
static const size_t OFF_G1    = 268435456;    // alias Z (dead after fused edge kernel)

typedef __attribute__((ext_vector_type(8))) short bf16x8;
typedef __attribute__((ext_vector_type(4))) float f32x4;

__device__ __forceinline__ float gelu_f(float v) {
    return v * 0.5f * (1.0f + erff(v * 0.7071067811865476f));
}
__device__ __forceinline__ unsigned short f2bf(float f) {
    unsigned int u = __float_as_uint(f);
    unsigned int r = (u + 0x7FFFu + ((u >> 16) & 1u)) >> 16;
    return (unsigned short)r;
}
__device__ __forceinline__ float bf2f(unsigned short h) {
    return __uint_as_float(((unsigned int)h) << 16);
}
__device__ __forceinline__ unsigned int pack2(unsigned short a, unsigned short b) {
    return (unsigned int)a | ((unsigned int)b << 16);
}
__device__ __forceinline__ void stage16(const void* g, void* l) {
    __builtin_amdgcn_global_load_lds(
        (const __attribute__((address_space(1))) unsigned int*)g,
        (__attribute__((address_space(3))) unsigned int*)l,
        16, 0, 0);
}
// float4 -> 2x(hi pair) + 2x(lo pair)
__device__ __forceinline__ void cvt4(const float4 v, unsigned int* hw, unsigned int* lw) {
    const unsigned short a = f2bf(v.x), b = f2bf(v.y), c = f2bf(v.z), d = f2bf(v.w);
    hw[0] = pack2(a, b); hw[1] = pack2(c, d);
    lw[0] = pack2(f2bf(v.x - bf2f(a)), f2bf(v.y - bf2f(b)));
    lw[1] = pack2(f2bf(v.z - bf2f(c)), f2bf(v.w - bf2f(d)));
}

// ---------------------------------------------------------------------------
// x fp32 [SEQ][256] -> xH/xL bf16 (wave per row)
// ---------------------------------------------------------------------------
__global__ __launch_bounds__(256) void conv_x(
    const float* __restrict__ x,
    unsigned short* __restrict__ xH, unsigned short* __restrict__ xL)
{
    const int wv = threadIdx.x >> 6;
    const int l  = threadIdx.x & 63;
    const int row = blockIdx.x * 4 + wv;
    const size_t base = (size_t)row * IN_DIM + l * 4;
    float4 v = *(const float4*)&x[base];
    unsigned short h0 = f2bf(v.x), h1 = f2bf(v.y), h2 = f2bf(v.z), h3 = f2bf(v.w);
    uint2 H, L;
    H.x = pack2(h0, h1); H.y = pack2(h2, h3);
    L.x = pack2(f2bf(v.x - bf2f(h0)), f2bf(v.y - bf2f(h1)));
    L.y = pack2(f2bf(v.z - bf2f(h2)), f2bf(v.w - bf2f(h3)));
    *(uint2*)&xH[base] = H;
    *(uint2*)&xL[base] = L;
}

// ---------------------------------------------------------------------------
// Weight convert: W[K][N] fp32 -> WT hi/lo bf16 [N][K]
// ---------------------------------------------------------------------------
__global__ __launch_bounds__(256) void conv_w(
    const float* __restrict__ W, unsigned short* __restrict__ WTh,
    unsigned short* __restrict__ WTl, int K, int N)
{
    int idx = blockIdx.x * 256 + threadIdx.x;
    if (idx >= K * N) return;
    int k = idx / N, n = idx % N;
    float v = W[idx];
    unsigned short h = f2bf(v);
    WTh[(size_t)n * K + k] = h;
    WTl[(size_t)n * K + k] = f2bf(v - bf2f(h));
}

// ---------------------------------------------------------------------------
// bconst[n] = b0[n] + sum_j sin(om_j)*w0[640+j][n] + cos(om_j)*w0[704+j][n]
// ---------------------------------------------------------------------------
__global__ __launch_bounds__(256) void bias_fold(
    const float* __restrict__ w0, const float* __restrict__ b0,
    float* __restrict__ bconst)
{
    int n = blockIdx.x * 256 + threadIdx.x;
    if (n >= H0_DIM) return;
    float s = b0[n];
    for (int j = 0; j < 64; ++j) {
        float om = exp2f((float)j * (-13.287712379549449f / 64.0f));
        s += sinf(om) * w0[(size_t)(640 + j) * H0_DIM + n];
        s += cosf(om) * w0[(size_t)(704 + j) * H0_DIM + n];
    }
    bconst[n] = s;
}

// ---------------------------------------------------------------------------
// start[q] = first edge index with qidx >= q (qidx sorted ascending)
// ---------------------------------------------------------------------------
__global__ __launch_bounds__(256) void seg_offsets(
    const int* __restrict__ edges, int* __restrict__ start)
{
    int e = blockIdx.x * 256 + threadIdx.x;
    if (e > NE_) return;
    int qc = (e < NE_) ? edges[2 * e] : NQ_;
    int qp = (e > 0) ? edges[2 * e - 2] : -1;
    for (int q = qp + 1; q <= qc; ++q) start[q] = e;
}

// ---------------------------------------------------------------------------
// PE build for window: rows i in [0,QWIN), query q = qbase+i, cols 0..383.
// ---------------------------------------------------------------------------
__global__ __launch_bounds__(256) void build_pe(
    const float* __restrict__ qpos, int qbase,
    unsigned short* __restrict__ peH, unsigned short* __restrict__ peL)
{
    const int wv = threadIdx.x >> 6;
    const int l  = threadIdx.x & 63;
    const int i  = blockIdx.x * 4 + wv;
    const int i0 = l * 8;
    if (i0 >= PE_K) return;
    const int q  = qbase + i;
    const size_t base = (size_t)i * PE_K;

    const int cc = i0 >> 7;          // coord 0..2
    const int j0 = i0 & 127;
    const float cv = qpos[q * 3 + cc] * 0.01f - 1.0f;
    const bool is_sin = (j0 < 64);
    const int jj0 = j0 & 63;
    unsigned int hw[4], lw[4];
    #pragma unroll
    for (int p2 = 0; p2 < 4; ++p2) {
        unsigned short hh[2], ll[2];
        #pragma unroll
        for (int s = 0; s < 2; ++s) {
            int jj = jj0 + p2 * 2 + s;
            float om  = exp2f((float)jj * (-13.287712379549449f / 64.0f));
            float arg = cv * om;
            float v   = is_sin ? __sinf(arg) : __cosf(arg);
            unsigned short h = f2bf(v);
            hh[s] = h; ll[s] = f2bf(v - bf2f(h));
        }
        hw[p2] = pack2(hh[0], hh[1]);
        lw[p2] = pack2(ll[0], ll[1]);
    }
    uint4 H, L;
    H.x = hw[0]; H.y = hw[1]; H.z = hw[2]; H.w = hw[3];
    L.x = lw[0]; L.y = lw[1]; L.z = lw[2]; L.w = lw[3];
    *(uint4*)&peH[base + i0] = H;
    *(uint4*)&peL[base + i0] = L;
}

// ---------------------------------------------------------------------------
// Split-bf16 MFMA GEMM (3 passes AhBh+AhBl+AlBh). 128x128 tile, BK=32.
// v9: DOUBLE-BUFFERED staging with ONE __syncthreads per K-step.
//   stage(k+1) -> buf (k+1)&1 issued at top of step k; the end-of-step
//   __syncthreads (full vmcnt drain) publishes it for step k+1. Race-free:
//   step k reads buf k&1; staging targets buf (k+1)&1 whose readers
//   (step k-1) completed at the previous barrier. Staging is VGPR-free
//   (global_load_lds), so prefetch costs no registers.
// LDS 64 KB dynamic (2 x [4][128][32] shorts); 2 blocks/CU (VGPR-limited).
// Used for the Z build (PE @ W0b') and the pred0 GEMM.
// ---------------------------------------------------------------------------
template <int ACT, int OUT_MODE, int GATHER>
__global__ __launch_bounds__(256) void gemm_mfma(
    const unsigned short* __restrict__ Ah, const unsigned short* __restrict__ Al,
    const unsigned short* __restrict__ Bh, const unsigned short* __restrict__ Bl,
    const float* __restrict__ bias,
    float* __restrict__ Cf, unsigned short* __restrict__ ChO, unsigned short* __restrict__ ClO,
    int M, int K, int N,
    const int* __restrict__ gp, const float* __restrict__ Zw)
{
    extern __shared__ __align__(16) short gsm[];   // 2 bufs x 16384 shorts = 64 KB

    const int tid = threadIdx.x;
    const int w   = tid >> 6;
    const int l   = tid & 63;
    const int l16 = l & 15;
    const int lq  = l >> 4;
    const int bm  = blockIdx.y * 128;
    const int bn  = blockIdx.x * 128;
    const int wm  = (w & 1) * 64;
    const int wn  = (w >> 1) * 64;

    f32x4 acc[4][4];
    #pragma unroll
    for (int i = 0; i < 4; ++i)
        #pragma unroll
        for (int j = 0; j < 4; ++j)
            acc[i][j] = (f32x4){0.f, 0.f, 0.f, 0.f};

    const int jrow = l >> 2;
    const int jkc  = l & 3;
    const int t0 = w * 2, t1 = t0 + 1;
    const int r0 = t0 * 16 + jrow, r1 = t1 * 16 + jrow;

    size_t arow0, arow1;
    if (GATHER) {
        arow0 = (size_t)gp[2 * (bm + r0) + 1] * K;
        arow1 = (size_t)gp[2 * (bm + r1) + 1] * K;
    } else {
        arow0 = (size_t)(bm + r0) * K;
        arow1 = (size_t)(bm + r1) * K;
    }
    const size_t brow0 = (size_t)(bn + r0) * K;
    const size_t brow1 = (size_t)(bn + r1) * K;

    auto stg = [&](int k, int cb) {
        const int ko = (k << 5) + jkc * 8;
        short* B = gsm + cb * 16384;     // planes: Ah@0 Al@4096 Bh@8192 Bl@12288
        stage16(Ah + arow0 + ko, B + t0 * 512);
        stage16(Al + arow0 + ko, B + 4096 + t0 * 512);
        stage16(Bh + brow0 + ko, B + 8192 + t0 * 512);
        stage16(Bl + brow0 + ko, B + 12288 + t0 * 512);
        stage16(Ah + arow1 + ko, B + t1 * 512);
        stage16(Al + arow1 + ko, B + 4096 + t1 * 512);
        stage16(Bh + brow1 + ko, B + 8192 + t1 * 512);
        stage16(Bl + brow1 + ko, B + 12288 + t1 * 512);
    };

    const int NK = K >> 5;
    stg(0, 0);
    __syncthreads();                     // publish buf0

    #pragma unroll 1
    for (int ks = 0; ks < NK; ++ks) {
        const int cb = ks & 1;
        if (ks + 1 < NK) stg(ks + 1, cb ^ 1);    // fly during this step's MFMAs

        const short* B = gsm + cb * 16384;
        bf16x8 ah[4], al[4], bh[4], bl[4];
        #pragma unroll
        for (int i = 0; i < 4; ++i) {
            const int roA = (wm + i * 16 + l16) * 32 + lq * 8;
            const int roB = (wn + i * 16 + l16) * 32 + lq * 8;
            ah[i] = *(const bf16x8*)&B[roA];
            al[i] = *(const bf16x8*)&B[4096 + roA];
            bh[i] = *(const bf16x8*)&B[8192 + roB];
            bl[i] = *(const bf16x8*)&B[12288 + roB];
        }
        #pragma unroll
        for (int i = 0; i < 4; ++i)
            #pragma unroll
            for (int j = 0; j < 4; ++j) {
                acc[i][j] = __builtin_amdgcn_mfma_f32_16x16x32_bf16(ah[i], bh[j], acc[i][j], 0, 0, 0);
                acc[i][j] = __builtin_amdgcn_mfma_f32_16x16x32_bf16(ah[i], bl[j], acc[i][j], 0, 0, 0);
                acc[i][j] = __builtin_amdgcn_mfma_f32_16x16x32_bf16(al[i], bh[j], acc[i][j], 0, 0, 0);
            }
        __syncthreads();   // reads of buf cb done; stage(ks+1) drained
    }

    if (OUT_MODE == 0) {
        #pragma unroll
        for (int j = 0; j < 4; ++j) {
            int n = bn + wn + j * 16 + l16;
            float bv = bias[n];
            #pragma unroll
            for (int i = 0; i < 4; ++i) {
                int mrow = bm + wm + i * 16 + lq * 4;
                #pragma unroll
                for (int r = 0; r < 4; ++r) {
                    float v = acc[i][j][r] + bv;
                    if (ACT) v = gelu_f(v);
                    Cf[(size_t)(mrow + r) * N + n] = v;
                }
            }
        }
    }
}

// ---------------------------------------------------------------------------
// FUSED edge MLP, v2 (R2-exact, best measured: 795 us, no spill, VGPR 124).
// 64-edge tiles, 256 threads (4 waves), 64 KB LDS -> 2 blocks/CU.
//   h0 = gelu(x[gidx] @ W0a + Z[qidx])   (512 cols in 4 chunks of 128)
//   h1 = gelu(h0 @ W1 + b1)              (256, register-resident)
//   h2 = h1 @ W2 + b2                    (128, fp32 -> global)
// All operands LDS-staged via global_load_lds (the register-free prefetch:
// R8 proved B-from-global cannot pipeline within the ~250-reg budget).
// LDS (64 KB): stg 32 KB (staging / per-wave lbuf) + h0 hi/lo [64][128] 32 KB.
// lbuf is [64][32] f32 per wave with 16B-unit XOR swizzle (u ^ (row&7)).
// ---------------------------------------------------------------------------
__global__ __launch_bounds__(256, 2) void fused_edge(
    const unsigned short* __restrict__ xHg, const unsigned short* __restrict__ xLg,
    const unsigned short* __restrict__ w0aHg, const unsigned short* __restrict__ w0aLg,
    const unsigned short* __restrict__ w1Hg, const unsigned short* __restrict__ w1Lg,
    const unsigned short* __restrict__ w2Hg, const unsigned short* __restrict__ w2Lg,
    const float* __restrict__ Zg, const float* __restrict__ b1g,
    const float* __restrict__ b2g, const int* __restrict__ gp,
    float* __restrict__ h2g)
{
    extern __shared__ __align__(16) short smem[];
    short* stg = smem;                 // 16384 shorts = 32 KB staging / lbuf
    short* h0h = smem + 16384;         // [64][128] = 16 KB
    short* h0l = smem + 24576;         // 16 KB

    const int tid = threadIdx.x;
    const int w   = tid >> 6;
    const int l   = tid & 63;
    const int l16 = l & 15;
    const int lq  = l >> 4;
    const int bm  = blockIdx.x * 64;

    const int wn_p = w * 32;   // phase-1 / h2 col base
    const int wn1  = w * 64;   // h1 col base (0..255)

    // staging roles: thread covers row rx, 16B unit ux -> dst = base + tid*16B
    const int rx = tid >> 2;
    const int ux = tid & 3;
    const size_t xoff = (size_t)gp[2 * (bm + rx) + 1] * IN_DIM + ux * 8;
    const int q_e = gp[2 * (bm + l)];
    float* lbuf = ((float*)stg) + w * 2048;   // [64][32] f32 per wave

    short* stgAh  = stg;            // [64][32]
    short* stgAl  = stg + 2048;
    short* stgBh  = stg + 4096;     // [128][32]
    short* stgBl  = stg + 8192;
    short* stgW1h = stg;            // [256][32]
    short* stgW1l = stg + 8192;
    short* stgW2h = stg;            // [128][32]
    short* stgW2l = stg + 4096;

    f32x4 h1acc[4][4];
    #pragma unroll
    for (int i = 0; i < 4; ++i)
        #pragma unroll
        for (int j = 0; j < 4; ++j)
            h1acc[i][j] = (f32x4){0.f, 0.f, 0.f, 0.f};

    for (int c = 0; c < 4; ++c) {
        f32x4 acc1[4][2];
        #pragma unroll
        for (int i = 0; i < 4; ++i)
            #pragma unroll
            for (int j = 0; j < 2; ++j)
                acc1[i][j] = (f32x4){0.f, 0.f, 0.f, 0.f};

        // ---- phase 1: h0c[64][128] = x[gidx] @ W0a_c, K=256 ----
        {
            const size_t wo = (size_t)(c * 128 + rx) * IN_DIM + ux * 8;
            stage16(xHg + xoff, stgAh + tid * 8);
            stage16(xLg + xoff, stgAl + tid * 8);
            stage16(w0aHg + wo,                      stgBh + tid * 8);
            stage16(w0aLg + wo,                      stgBl + tid * 8);
            stage16(w0aHg + wo + (size_t)64 * IN_DIM, stgBh + 2048 + tid * 8);
            stage16(w0aLg + wo + (size_t)64 * IN_DIM, stgBl + 2048 + tid * 8);
        }
        __syncthreads();
        for (int ks = 0; ks < 8; ++ks) {
            bf16x8 ah[4], al[4], bh[2], bl[2];
            #pragma unroll
            for (int i = 0; i < 4; ++i) {
                const int ro = (i * 16 + l16) * 32 + lq * 8;
                ah[i] = *(const bf16x8*)&stgAh[ro];
                al[i] = *(const bf16x8*)&stgAl[ro];
            }
            #pragma unroll
            for (int j = 0; j < 2; ++j) {
                const int ro = (wn_p + j * 16 + l16) * 32 + lq * 8;
                bh[j] = *(const bf16x8*)&stgBh[ro];
                bl[j] = *(const bf16x8*)&stgBl[ro];
            }
            __syncthreads();
            if (ks < 7) {
                const int ko = (ks + 1) * 32;
                const size_t wo = (size_t)(c * 128 + rx) * IN_DIM + ko + ux * 8;
                stage16(xHg + xoff + ko, stgAh + tid * 8);
                stage16(xLg + xoff + ko, stgAl + tid * 8);
                stage16(w0aHg + wo,                      stgBh + tid * 8);
                stage16(w0aLg + wo,                      stgBl + tid * 8);
                stage16(w0aHg + wo + (size_t)64 * IN_DIM, stgBh + 2048 + tid * 8);
                stage16(w0aLg + wo + (size_t)64 * IN_DIM, stgBl + 2048 + tid * 8);
            }
            #pragma unroll
            for (int i = 0; i < 4; ++i)
                #pragma unroll
                for (int j = 0; j < 2; ++j) {
                    acc1[i][j] = __builtin_amdgcn_mfma_f32_16x16x32_bf16(ah[i], bh[j], acc1[i][j], 0, 0, 0);
                    acc1[i][j] = __builtin_amdgcn_mfma_f32_16x16x32_bf16(ah[i], bl[j], acc1[i][j], 0, 0, 0);
                    acc1[i][j] = __builtin_amdgcn_mfma_f32_16x16x32_bf16(al[i], bh[j], acc1[i][j], 0, 0, 0);
                }
            __syncthreads();
        }

        // ---- epilogue: +Z, gelu, cvt -> h0h/h0l (swizzled) ----
        #pragma unroll
        for (int j = 0; j < 2; ++j)
            #pragma unroll
            for (int i = 0; i < 4; ++i)
                #pragma unroll
                for (int r = 0; r < 4; ++r) {
                    const int rowq = i * 16 + lq * 4 + r;
                    const int u = j * 4 + (l16 >> 2);
                    lbuf[rowq * 32 + (((u ^ (rowq & 7)) << 2) | (l16 & 3))] = acc1[i][j][r];
                }
        __syncthreads();
        {
            const float* zrow = Zg + (size_t)q_e * H0_DIM + c * 128 + wn_p;
            #pragma unroll
            for (int g = 0; g < 2; ++g) {
                unsigned int hw[8], lw[8];
                #pragma unroll
                for (int c2 = 0; c2 < 4; ++c2) {
                    const int cq = g * 4 + c2;
                    float4 v = *(const float4*)&lbuf[l * 32 + ((cq ^ (l & 7)) << 2)];
                    const float4 z = *(const float4*)&zrow[cq * 4];
                    v.x = gelu_f(v.x + z.x); v.y = gelu_f(v.y + z.y);
                    v.z = gelu_f(v.z + z.z); v.w = gelu_f(v.w + z.w);
                    cvt4(v, &hw[c2 * 2], &lw[c2 * 2]);
                }
                const int u0 = (wn_p >> 3) + g * 2;
                const int o0 = l * 128 + (((u0    ) ^ (l & 7)) << 3);
                const int o1 = l * 128 + (((u0 + 1) ^ (l & 7)) << 3);
                uint4 H0, H1, L0, L1;
                H0.x = hw[0]; H0.y = hw[1]; H0.z = hw[2]; H0.w = hw[3];
                H1.x = hw[4]; H1.y = hw[5]; H1.z = hw[6]; H1.w = hw[7];
                L0.x = lw[0]; L0.y = lw[1]; L0.z = lw[2]; L0.w = lw[3];
                L1.x = lw[4]; L1.y = lw[5]; L1.z = lw[6]; L1.w = lw[7];
                *(uint4*)&h0h[o0] = H0; *(uint4*)&h0h[o1] = H1;
                *(uint4*)&h0l[o0] = L0; *(uint4*)&h0l[o1] = L1;
            }
        }
        __syncthreads();

        // ---- h1 partial: h1acc += h0c @ W1[:, c-block of K], K=128 ----
        {
            #pragma unroll
            for (int p = 0; p < 4; ++p) {
                const size_t o = (size_t)(rx + 64 * p) * H0_DIM + c * 128 + ux * 8;
                stage16(w1Hg + o, stgW1h + p * 2048 + tid * 8);
                stage16(w1Lg + o, stgW1l + p * 2048 + tid * 8);
            }
        }
        __syncthreads();
        for (int ks = 0; ks < 4; ++ks) {
            bf16x8 ah[4], al[4], bh[4], bl[4];
            #pragma unroll
            for (int i = 0; i < 4; ++i) {
                const int row = i * 16 + l16;
                const int uo = ((ks * 4 + lq) ^ (row & 7)) << 3;
                ah[i] = *(const bf16x8*)&h0h[row * 128 + uo];
                al[i] = *(const bf16x8*)&h0l[row * 128 + uo];
            }
            #pragma unroll
            for (int j = 0; j < 4; ++j) {
                const int ro = (wn1 + j * 16 + l16) * 32 + lq * 8;
                bh[j] = *(const bf16x8*)&stgW1h[ro];
                bl[j] = *(const bf16x8*)&stgW1l[ro];
            }
            __syncthreads();
            if (ks < 3) {
                #pragma unroll
                for (int p = 0; p < 4; ++p) {
                    const size_t o = (size_t)(rx + 64 * p) * H0_DIM + c * 128 + (ks + 1) * 32 + ux * 8;
                    stage16(w1Hg + o, stgW1h + p * 2048 + tid * 8);
                    stage16(w1Lg + o, stgW1l + p * 2048 + tid * 8);
                }
            }
            #pragma unroll
            for (int i = 0; i < 4; ++i)
                #pragma unroll
                for (int j = 0; j < 4; ++j) {
                    h1acc[i][j] = __builtin_amdgcn_mfma_f32_16x16x32_bf16(ah[i], bh[j], h1acc[i][j], 0, 0, 0);
                    h1acc[i][j] = __builtin_amdgcn_mfma_f32_16x16x32_bf16(ah[i], bl[j], h1acc[i][j], 0, 0, 0);
                    h1acc[i][j] = __builtin_amdgcn_mfma_f32_16x16x32_bf16(al[i], bh[j], h1acc[i][j], 0, 0, 0);
                }
            __syncthreads();
        }
    }

    // ---- h2 = gelu(h1 + b1) @ W2 + b2, K=256 in two 128-k halves ----
    f32x4 acc2[4][2];
    #pragma unroll
    for (int i = 0; i < 4; ++i)
        #pragma unroll
        for (int j = 0; j < 2; ++j)
            acc2[i][j] = (f32x4){0.f, 0.f, 0.f, 0.f};

    for (int kh = 0; kh < 2; ++kh) {
        const bool my = ((w >> 1) == kh);   // wave w owns h1 cols w*64..w*64+63
        #pragma unroll
        for (int j2 = 0; j2 < 2; ++j2) {
            if (my) {
                #pragma unroll
                for (int jj = 0; jj < 2; ++jj) {
                    const int j = j2 * 2 + jj;
                    const float bv = b1g[wn1 + j * 16 + l16];
                    #pragma unroll
                    for (int i = 0; i < 4; ++i)
                        #pragma unroll
                        for (int r = 0; r < 4; ++r) {
                            const int rowq = i * 16 + lq * 4 + r;
                            const int u = jj * 4 + (l16 >> 2);
                            lbuf[rowq * 32 + (((u ^ (rowq & 7)) << 2) | (l16 & 3))] =
                                gelu_f(h1acc[i][j][r] + bv);
                        }
                }
            }
            __syncthreads();
            if (my) {
                const int colb = (w & 1) * 64 + j2 * 32;
                #pragma unroll
                for (int g = 0; g < 2; ++g) {
                    unsigned int hw[8], lw[8];
                    #pragma unroll
                    for (int c2 = 0; c2 < 4; ++c2) {
                        const int cq = g * 4 + c2;
                        float4 v = *(const float4*)&lbuf[l * 32 + ((cq ^ (l & 7)) << 2)];
                        cvt4(v, &hw[c2 * 2], &lw[c2 * 2]);
                    }
                    const int u0 = ((colb + g * 16) >> 3);
                    const int o0 = l * 128 + (((u0    ) ^ (l & 7)) << 3);
                    const int o1 = l * 128 + (((u0 + 1) ^ (l & 7)) << 3);
                    uint4 H0, H1, L0, L1;
                    H0.x = hw[0]; H0.y = hw[1]; H0.z = hw[2]; H0.w = hw[3];
                    H1.x = hw[4]; H1.y = hw[5]; H1.z = hw[6]; H1.w = hw[7];
                    L0.x = lw[0]; L0.y = lw[1]; L0.z = lw[2]; L0.w = lw[3];
                    L1.x = lw[4]; L1.y = lw[5]; L1.z = lw[6]; L1.w = lw[7];
                    *(uint4*)&h0h[o0] = H0; *(uint4*)&h0h[o1] = H1;
                    *(uint4*)&h0l[o0] = L0; *(uint4*)&h0l[o1] = L1;
                }
            }
            __syncthreads();
        }

        // h2 partial K-loop (K=128): A = h1 half in h0 bufs, B = W2 staged
        {
            #pragma unroll
            for (int p = 0; p < 2; ++p) {
                const size_t o = (size_t)(rx + 64 * p) * H1_DIM + kh * 128 + ux * 8;
                stage16(w2Hg + o, stgW2h + p * 2048 + tid * 8);
                stage16(w2Lg + o, stgW2l + p * 2048 + tid * 8);
            }
        }
        __syncthreads();
        for (int ks = 0; ks < 4; ++ks) {
            bf16x8 ah[4], al[4], bh[2], bl[2];
            #pragma unroll
            for (int i = 0; i < 4; ++i) {
                const int row = i * 16 + l16;
                const int uo = ((ks * 4 + lq) ^ (row & 7)) << 3;
                ah[i] = *(const bf16x8*)&h0h[row * 128 + uo];
                al[i] = *(const bf16x8*)&h0l[row * 128 + uo];
            }
            #pragma unroll
            for (int j = 0; j < 2; ++j) {
                const int ro = (wn_p + j * 16 + l16) * 32 + lq * 8;
                bh[j] = *(const bf16x8*)&stgW2h[ro];
                bl[j] = *(const bf16x8*)&stgW2l[ro];
            }
            __syncthreads();
            if (ks < 3) {
                #pragma unroll
                for (int p = 0; p < 2; ++p) {
                    const size_t o = (size_t)(rx + 64 * p) * H1_DIM + kh * 128 + (ks + 1) * 32 + ux * 8;
                    stage16(w2Hg + o, stgW2h + p * 2048 + tid * 8);
                    stage16(w2Lg + o, stgW2l + p * 2048 + tid * 8);
                }
            }
            #pragma unroll
            for (int i = 0; i < 4; ++i)
                #pragma unroll
                for (int j = 0; j < 2; ++j) {
                    acc2[i][j] = __builtin_amdgcn_mfma_f32_16x16x32_bf16(ah[i], bh[j], acc2[i][j], 0, 0, 0);
                    acc2[i][j] = __builtin_amdgcn_mfma_f32_16x16x32_bf16(ah[i], bl[j], acc2[i][j], 0, 0, 0);
                    acc2[i][j] = __builtin_amdgcn_mfma_f32_16x16x32_bf16(al[i], bh[j], acc2[i][j], 0, 0, 0);
                }
            __syncthreads();
        }
    }

    // ---- h2 epilogue: + b2, fp32 store ----
    #pragma unroll
    for (int j = 0; j < 2; ++j) {
        const int n = wn_p + j * 16 + l16;
        const float bv = b2g[n];
        #pragma unroll
        for (int i = 0; i < 4; ++i) {
            const int er = bm + i * 16 + lq * 4;
            #pragma unroll
            for (int r = 0; r < 4; ++r)
                h2g[(size_t)(er + r) * BOT + n] = acc2[i][j][r] + bv;
        }
    }
}

// ---------------------------------------------------------------------------
// segment mean via precomputed offsets
// ---------------------------------------------------------------------------
__global__ __launch_bounds__(256) void seg_mean(
    const int* __restrict__ start, const float* __restrict__ h2,
    unsigned short* __restrict__ mH, unsigned short* __restrict__ mL)
{
    const int t = threadIdx.x;
    const int q = blockIdx.x * 8 + (t >> 5);
    const int quad = t & 31;
    const int s = start[q];
    const int e = start[q + 1];

    float4 acc = make_float4(0.f, 0.f, 0.f, 0.f);
    for (int i = s; i < e; ++i) {
        const float4 v = *(const float4*)&h2[(size_t)i * BOT + quad * 4];
        acc.x += v.x; acc.y += v.y; acc.z += v.z; acc.w += v.w;
    }
    const float inv = 1.0f / (float)((e - s) > 0 ? (e - s) : 1);
    float m0 = acc.x * inv, m1 = acc.y * inv, m2 = acc.z * inv, m3 = acc.w * inv;
    unsigned short h0 = f2bf(m0), h1 = f2bf(m1), h2s = f2bf(m2), h3 = f2bf(m3);
    uint2 H, L;
    H.x = pack2(h0, h1); H.y = pack2(h2s, h3);
    L.x = pack2(f2bf(m0 - bf2f(h0)), f2bf(m1 - bf2f(h1)));
    L.y = pack2(f2bf(m2 - bf2f(h2s)), f2bf(m3 - bf2f(h3)));
    *(uint2*)&mH[(size_t)q * BOT + quad * 4] = H;
    *(uint2*)&mL[(size_t)q * BOT + quad * 4] = L;
}

// ---------------------------------------------------------------------------
// out[NQ,4] = g1[NQ,256] @ pw1[256,4] + pb1 : one wave per row
// ---------------------------------------------------------------------------
__global__ __launch_bounds__(256) void pred1_kernel(
    const float* __restrict__ g1, const float* __restrict__ w,
    const float* __restrict__ b, float* __restrict__ out)
{
    const int wave = threadIdx.x >> 6;
    const int lane = threadIdx.x & 63;
    const int row  = blockIdx.x * 4 + wave;

    const float* g = g1 + (size_t)row * 256;
    float a0 = 0, a1 = 0, a2 = 0, a3 = 0;
    #pragma unroll
    for (int i = 0; i < 4; ++i) {
        int k = lane + 64 * i;
        float gv = g[k];
        const float* wr = w + k * 4;
        a0 = fmaf(gv, wr[0], a0);
        a1 = fmaf(gv, wr[1], a1);
        a2 = fmaf(gv, wr[2], a2);
        a3 = fmaf(gv, wr[3], a3);
    }
    #pragma unroll
    for (int off = 32; off > 0; off >>= 1) {
        a0 += __shfl_down(a0, off, 64);
        a1 += __shfl_down(a1, off, 64);
        a2 += __shfl_down(a2, off, 64);
        a3 += __shfl_down(a3, off, 64);
    }
    if (lane == 0) {
        float4 o = {a0 + b[0], a1 + b[1], a2 + b[2], a3 + b[3]};
        *(float4*)&out[(size_t)row * 4] = o;
    }
}

// ---------------------------------------------------------------------------
extern "C" void kernel_launch(void* const* d_in, const int* in_sizes, int n_in,
                              void* d_out, int out_size, void* d_ws, size_t ws_size,
                              hipStream_t stream)
{
    const float* x    = (const float*)d_in[0];
    const float* qpos = (const float*)d_in[1];
    const int*   edges= (const int*)  d_in[2];
    const float* w0   = (const float*)d_in[3];
    const float* b0   = (const float*)d_in[4];
    const float* w1   = (const float*)d_in[5];
    const float* b1   = (const float*)d_in[6];
    const float* w2   = (const float*)d_in[7];
    const float* b2   = (const float*)d_in[8];
    const float* pw0  = (const float*)d_in[9];
    const float* pb0  = (const float*)d_in[10];
    const float* pw1  = (const float*)d_in[11];
    const float* pb1  = (const float*)d_in[12];
    float* out = (float*)d_out;

    char* ws = (char*)d_ws;
    unsigned short* xH    = (unsigned short*)(ws + OFF_XH);
    unsigned short* xL    = (unsigned short*)(ws + OFF_XL);
    float*          Z     = (float*)(ws + OFF_Z);
    unsigned short* peH   = (unsigned short*)(ws + OFF_PEH);
    unsigned short* peL   = (unsigned short*)(ws + OFF_PEL);
    float*          h2    = (float*)(ws + OFF_H2);
    unsigned short* w0aH  = (unsigned short*)(ws + OFF_W0AH);
    unsigned short* w0aL  = (unsigned short*)(ws + OFF_W0AL);
    unsigned short* w0bH  = (unsigned short*)(ws + OFF_W0BH);
    unsigned short* w0bL  = (unsigned short*)(ws + OFF_W0BL);
    unsigned short* w1H   = (unsigned short*)(ws + OFF_W1H);
    unsigned short* w1L   = (unsigned short*)(ws + OFF_W1L);
    unsigned short* w2H   = (unsigned short*)(ws + OFF_W2H);
    unsigned short* w2L   = (unsigned short*)(ws + OFF_W2L);
    unsigned short* pw0H  = (unsigned short*)(ws + OFF_PW0H);
    unsigned short* pw0L  = (unsigned short*)(ws + OFF_PW0L);
    float*          bconst= (float*)(ws + OFF_BCONST);
    int*            start = (int*)(ws + OFF_START);
    unsigned short* meanH = (unsigned short*)(ws + OFF_MEANH);
    unsigned short* meanL = (unsigned short*)(ws + OFF_MEANL);
    float*          g1    = (float*)(ws + OFF_G1);

    // allow 64 KB dynamic LDS (once per process) for fused + both gemms
    static bool attr_done = false;
    if (!attr_done) {
        hipFuncSetAttribute(reinterpret_cast<const void*>(&fused_edge),
                            hipFuncAttributeMaxDynamicSharedMemorySize, 65536);
        hipFuncSetAttribute(reinterpret_cast<const void*>(&gemm_mfma<0, 0, 0>),
                            hipFuncAttributeMaxDynamicSharedMemorySize, 65536);
        hipFuncSetAttribute(reinterpret_cast<const void*>(&gemm_mfma<1, 0, 0>),
                            hipFuncAttributeMaxDynamicSharedMemorySize, 65536);
        attr_done = true;
    }

    // one-time conversions
    conv_x<<<SEQ_/4, 256, 0, stream>>>(x, xH, xL);
    conv_w<<<(IN_DIM*H0_DIM + 255)/256, 256, 0, stream>>>(w0, w0aH, w0aL, IN_DIM, H0_DIM);
    conv_w<<<(PE_K*H0_DIM + 255)/256, 256, 0, stream>>>(w0 + (size_t)IN_DIM*H0_DIM, w0bH, w0bL, PE_K, H0_DIM);
    conv_w<<<(H0_DIM*H1_DIM + 255)/256, 256, 0, stream>>>(w1, w1H, w1L, H0_DIM, H1_DIM);
    conv_w<<<(H1_DIM*BOT + 255)/256, 256, 0, stream>>>(w2, w2H, w2L, H1_DIM, BOT);
    conv_w<<<(BOT*H1_DIM + 255)/256, 256, 0, stream>>>(pw0, pw0H, pw0L, BOT, H1_DIM);
    bias_fold<<<2, 256, 0, stream>>>(w0, b0, bconst);
    seg_offsets<<<(NE_ + 1 + 255)/256, 256, 0, stream>>>(edges, start);

    // Z = PE @ W0b' + bconst for all queries (4 L3-resident PE windows)
    for (int wn = 0; wn < NWIN; ++wn) {
        build_pe<<<QWIN/4, 256, 0, stream>>>(qpos, wn * QWIN, peH, peL);
        gemm_mfma<0, 0, 0><<<dim3(H0_DIM/128, QWIN/128), 256, 65536, stream>>>(
            peH, peL, w0bH, w0bL, bconst, Z + (size_t)wn * QWIN * H0_DIM,
            nullptr, nullptr, QWIN, PE_K, H0_DIM, nullptr, nullptr);
    }

    // fused 3-layer edge MLP (R2-exact: 64-edge tiles, 2 blocks/CU)
    fused_edge<<<NE_/64, 256, 65536, stream>>>(
        xH, xL, w0aH, w0aL, w1H, w1L, w2H, w2L,
        Z, b1, b2, edges, h2);

    seg_mean<<<NQ_/8, 256, 0, stream>>>(start, h2, meanH, meanL);
    gemm_mfma<1, 0, 0><<<dim3(H1_DIM/128, NQ_/128), 256, 65536, stream>>>(
        meanH, meanL, pw0H, pw0L, pb0, g1, nullptr, nullptr,
        NQ_, BOT, H1_DIM, nullptr, nullptr);
    pred1_kernel<<<NQ_/4, 256, 0, stream>>>(g1, pw1, pb1, out);
}

// Round 10
// 1576.888 us; speedup vs baseline: 1.5555x; 1.0269x over previous
//
#include <hip/hip_runtime.h>
#include <cmath>

// Problem constants
#define IN_DIM   256
#define H0_DIM   512
#define H1_DIM   256
#define BOT      128
#define NQ_      131072
#define NE_      262144
#define SEQ_     262144
#define QWIN     32768
#define NWIN     (NQ_/QWIN)
#define PE_K     384          // PE cols 384..511 are constant -> folded into bias

// Workspace layout (bytes), ws = 1 GiB.
static const size_t OFF_XH    = 0;            // 262144*256*2 = 134217728
static const size_t OFF_XL    = 134217728;
static const size_t OFF_Z     = 268435456;    // 131072*512*4 = 268435456
static const size_t OFF_PEH   = 536870912;    // 32768*384*2 = 25165824
static const size_t OFF_PEL   = 562036736;
static const size_t OFF_H2    = 738197504;    // 262144*128*4 = 134217728
static const size_t OFF_W0AH  = 872415232;    // [512][256] 262144
static const size_t OFF_W0AL  = 872677376;
static const size_t OFF_W0BH  = 872939520;    // [512][384] 393216
static const size_t OFF_W0BL  = 873332736;
static const size_t OFF_W1H   = 873725952;    // [256][512] 262144
static const size_t OFF_W1L   = 873988096;
static const size_t OFF_W2H   = 874250240;    // [128][256] 65536
static const size_t OFF_W2L   = 874315776;
static const size_t OFF_PW0H  = 874381312;    // [256][128] 65536
static const size_t OFF_PW0L  = 874446848;
static const size_t OFF_BCONST= 874512384;    // 512*4
static const size_t OFF_START = 874514432;    // (NQ+1)*4
// post-loop aliases
static const size_t OFF_MEANH = 0;            // alias xH (dead after fused edge kernel)
static const size_t OFF_MEANL = 33554432;

typedef __attribute__((ext_vector_type(8))) short bf16x8;
typedef __attribute__((ext_vector_type(4))) float f32x4;

__device__ __forceinline__ float gelu_f(float v) {
    return v * 0.5f * (1.0f + erff(v * 0.7071067811865476f));
}
__device__ __forceinline__ unsigned short f2bf(float f) {
    unsigned int u = __float_as_uint(f);
    unsigned int r = (u + 0x7FFFu + ((u >> 16) & 1u)) >> 16;
    return (unsigned short)r;
}
__device__ __forceinline__ float bf2f(unsigned short h) {
    return __uint_as_float(((unsigned int)h) << 16);
}
__device__ __forceinline__ unsigned int pack2(unsigned short a, unsigned short b) {
    return (unsigned int)a | ((unsigned int)b << 16);
}
__device__ __forceinline__ void stage16(const void* g, void* l) {
    __builtin_amdgcn_global_load_lds(
        (const __attribute__((address_space(1))) unsigned int*)g,
        (__attribute__((address_space(3))) unsigned int*)l,
        16, 0, 0);
}
// float4 -> 2x(hi pair) + 2x(lo pair)
__device__ __forceinline__ void cvt4(const float4 v, unsigned int* hw, unsigned int* lw) {
    const unsigned short a = f2bf(v.x), b = f2bf(v.y), c = f2bf(v.z), d = f2bf(v.w);
    hw[0] = pack2(a, b); hw[1] = pack2(c, d);
    lw[0] = pack2(f2bf(v.x - bf2f(a)), f2bf(v.y - bf2f(b)));
    lw[1] = pack2(f2bf(v.z - bf2f(c)), f2bf(v.w - bf2f(d)));
}

// ---------------------------------------------------------------------------
// x fp32 [SEQ][256] -> xH/xL bf16 (wave per row)
// ---------------------------------------------------------------------------
__global__ __launch_bounds__(256) void conv_x(
    const float* __restrict__ x,
    unsigned short* __restrict__ xH, unsigned short* __restrict__ xL)
{
    const int wv = threadIdx.x >> 6;
    const int l  = threadIdx.x & 63;
    const int row = blockIdx.x * 4 + wv;
    const size_t base = (size_t)row * IN_DIM + l * 4;
    float4 v = *(const float4*)&x[base];
    unsigned short h0 = f2bf(v.x), h1 = f2bf(v.y), h2 = f2bf(v.z), h3 = f2bf(v.w);
    uint2 H, L;
    H.x = pack2(h0, h1); H.y = pack2(h2, h3);
    L.x = pack2(f2bf(v.x - bf2f(h0)), f2bf(v.y - bf2f(h1)));
    L.y = pack2(f2bf(v.z - bf2f(h2)), f2bf(v.w - bf2f(h3)));
    *(uint2*)&xH[base] = H;
    *(uint2*)&xL[base] = L;
}

// ---------------------------------------------------------------------------
// Weight convert: W[K][N] fp32 -> WT hi/lo bf16 [N][K]
// ---------------------------------------------------------------------------
__global__ __launch_bounds__(256) void conv_w(
    const float* __restrict__ W, unsigned short* __restrict__ WTh,
    unsigned short* __restrict__ WTl, int K, int N)
{
    int idx = blockIdx.x * 256 + threadIdx.x;
    if (idx >= K * N) return;
    int k = idx / N, n = idx % N;
    float v = W[idx];
    unsigned short h = f2bf(v);
    WTh[(size_t)n * K + k] = h;
    WTl[(size_t)n * K + k] = f2bf(v - bf2f(h));
}

// ---------------------------------------------------------------------------
// bconst[n] = b0[n] + sum_j sin(om_j)*w0[640+j][n] + cos(om_j)*w0[704+j][n]
// ---------------------------------------------------------------------------
__global__ __launch_bounds__(256) void bias_fold(
    const float* __restrict__ w0, const float* __restrict__ b0,
    float* __restrict__ bconst)
{
    int n = blockIdx.x * 256 + threadIdx.x;
    if (n >= H0_DIM) return;
    float s = b0[n];
    for (int j = 0; j < 64; ++j) {
        float om = exp2f((float)j * (-13.287712379549449f / 64.0f));
        s += sinf(om) * w0[(size_t)(640 + j) * H0_DIM + n];
        s += cosf(om) * w0[(size_t)(704 + j) * H0_DIM + n];
    }
    bconst[n] = s;
}

// ---------------------------------------------------------------------------
// start[q] = first edge index with qidx >= q (qidx sorted ascending)
// ---------------------------------------------------------------------------
__global__ __launch_bounds__(256) void seg_offsets(
    const int* __restrict__ edges, int* __restrict__ start)
{
    int e = blockIdx.x * 256 + threadIdx.x;
    if (e > NE_) return;
    int qc = (e < NE_) ? edges[2 * e] : NQ_;
    int qp = (e > 0) ? edges[2 * e - 2] : -1;
    for (int q = qp + 1; q <= qc; ++q) start[q] = e;
}

// ---------------------------------------------------------------------------
// PE build for window: rows i in [0,QWIN), query q = qbase+i, cols 0..383.
// ---------------------------------------------------------------------------
__global__ __launch_bounds__(256) void build_pe(
    const float* __restrict__ qpos, int qbase,
    unsigned short* __restrict__ peH, unsigned short* __restrict__ peL)
{
    const int wv = threadIdx.x >> 6;
    const int l  = threadIdx.x & 63;
    const int i  = blockIdx.x * 4 + wv;
    const int i0 = l * 8;
    if (i0 >= PE_K) return;
    const int q  = qbase + i;
    const size_t base = (size_t)i * PE_K;

    const int cc = i0 >> 7;          // coord 0..2
    const int j0 = i0 & 127;
    const float cv = qpos[q * 3 + cc] * 0.01f - 1.0f;
    const bool is_sin = (j0 < 64);
    const int jj0 = j0 & 63;
    unsigned int hw[4], lw[4];
    #pragma unroll
    for (int p2 = 0; p2 < 4; ++p2) {
        unsigned short hh[2], ll[2];
        #pragma unroll
        for (int s = 0; s < 2; ++s) {
            int jj = jj0 + p2 * 2 + s;
            float om  = exp2f((float)jj * (-13.287712379549449f / 64.0f));
            float arg = cv * om;
            float v   = is_sin ? __sinf(arg) : __cosf(arg);
            unsigned short h = f2bf(v);
            hh[s] = h; ll[s] = f2bf(v - bf2f(h));
        }
        hw[p2] = pack2(hh[0], hh[1]);
        lw[p2] = pack2(ll[0], ll[1]);
    }
    uint4 H, L;
    H.x = hw[0]; H.y = hw[1]; H.z = hw[2]; H.w = hw[3];
    L.x = lw[0]; L.y = lw[1]; L.z = lw[2]; L.w = lw[3];
    *(uint4*)&peH[base + i0] = H;
    *(uint4*)&peL[base + i0] = L;
}

// ---------------------------------------------------------------------------
// Split-bf16 MFMA GEMM (3 passes AhBh+AhBl+AlBh). 128x128 tile, BK=32.
// R2-exact: A and B both LDS-staged (8x stage16/step), 2-barrier K-loop,
// static 32 KB LDS -> 3 blocks/CU (R9 proved 64 KB dbuf loses occupancy).
// Used for the Z build (PE @ W0b').
// ---------------------------------------------------------------------------
template <int ACT>
__global__ __launch_bounds__(256) void gemm_mfma(
    const unsigned short* __restrict__ Ah, const unsigned short* __restrict__ Al,
    const unsigned short* __restrict__ Bh, const unsigned short* __restrict__ Bl,
    const float* __restrict__ bias, float* __restrict__ Cf,
    int M, int K, int N)
{
    __shared__ __align__(16) short lds[4][128][32];   // 32 KB

    const int tid = threadIdx.x;
    const int w   = tid >> 6;
    const int l   = tid & 63;
    const int l16 = l & 15;
    const int lq  = l >> 4;
    const int bm  = blockIdx.y * 128;
    const int bn  = blockIdx.x * 128;
    const int wm  = (w & 1) * 64;
    const int wn  = (w >> 1) * 64;

    f32x4 acc[4][4];
    #pragma unroll
    for (int i = 0; i < 4; ++i)
        #pragma unroll
        for (int j = 0; j < 4; ++j)
            acc[i][j] = (f32x4){0.f, 0.f, 0.f, 0.f};

    const int jrow = l >> 2;
    const int jkc  = l & 3;
    const int t0 = w * 2, t1 = t0 + 1;
    const int r0 = t0 * 16 + jrow, r1 = t1 * 16 + jrow;

    const size_t arow0 = (size_t)(bm + r0) * K;
    const size_t arow1 = (size_t)(bm + r1) * K;
    const size_t brow0 = (size_t)(bn + r0) * K;
    const size_t brow1 = (size_t)(bn + r1) * K;
    short* d00 = &lds[0][0][0] + t0 * 512;
    short* d01 = &lds[1][0][0] + t0 * 512;
    short* d02 = &lds[2][0][0] + t0 * 512;
    short* d03 = &lds[3][0][0] + t0 * 512;
    short* d10 = &lds[0][0][0] + t1 * 512;
    short* d11 = &lds[1][0][0] + t1 * 512;
    short* d12 = &lds[2][0][0] + t1 * 512;
    short* d13 = &lds[3][0][0] + t1 * 512;

    for (int k0 = 0; k0 < K; k0 += 32) {
        const int ko = k0 + jkc * 8;
        stage16(Ah + arow0 + ko, d00);
        stage16(Al + arow0 + ko, d01);
        stage16(Bh + brow0 + ko, d02);
        stage16(Bl + brow0 + ko, d03);
        stage16(Ah + arow1 + ko, d10);
        stage16(Al + arow1 + ko, d11);
        stage16(Bh + brow1 + ko, d12);
        stage16(Bl + brow1 + ko, d13);
        __syncthreads();

        bf16x8 ah[4], al[4], bh[4], bl[4];
        #pragma unroll
        for (int i = 0; i < 4; ++i) {
            ah[i] = *(const bf16x8*)&lds[0][wm + i*16 + l16][lq*8];
            al[i] = *(const bf16x8*)&lds[1][wm + i*16 + l16][lq*8];
            bh[i] = *(const bf16x8*)&lds[2][wn + i*16 + l16][lq*8];
            bl[i] = *(const bf16x8*)&lds[3][wn + i*16 + l16][lq*8];
        }
        #pragma unroll
        for (int i = 0; i < 4; ++i)
            #pragma unroll
            for (int j = 0; j < 4; ++j) {
                acc[i][j] = __builtin_amdgcn_mfma_f32_16x16x32_bf16(ah[i], bh[j], acc[i][j], 0, 0, 0);
                acc[i][j] = __builtin_amdgcn_mfma_f32_16x16x32_bf16(ah[i], bl[j], acc[i][j], 0, 0, 0);
                acc[i][j] = __builtin_amdgcn_mfma_f32_16x16x32_bf16(al[i], bh[j], acc[i][j], 0, 0, 0);
            }
        __syncthreads();
    }

    #pragma unroll
    for (int j = 0; j < 4; ++j) {
        int n = bn + wn + j * 16 + l16;
        float bv = bias[n];
        #pragma unroll
        for (int i = 0; i < 4; ++i) {
            int mrow = bm + wm + i * 16 + lq * 4;
            #pragma unroll
            for (int r = 0; r < 4; ++r) {
                float v = acc[i][j][r] + bv;
                if (ACT) v = gelu_f(v);
                Cf[(size_t)(mrow + r) * N + n] = v;
            }
        }
    }
}

// ---------------------------------------------------------------------------
// FUSED pred0+pred1: per 128-query block,
//   g = gelu(mean @ pw0 + pb0)  (N=256 in two 128-col halves, K=128)
//   out = g @ pw1 + pb1         (256 -> 4, contracted in the epilogue:
//       per-lane partials -> shfl_xor reduce over the 16 lanes sharing lq ->
//       LDS scratch combine across the two n-wave-groups)
// Skips the g1 intermediate entirely (saves 268 MB HBM round-trip).
// K-loop body is the R2-proven gemm pattern (A=mean, B=pw0 staged, 32 KB).
// ---------------------------------------------------------------------------
__global__ __launch_bounds__(256) void pred_fused(
    const unsigned short* __restrict__ Ah, const unsigned short* __restrict__ Al,
    const unsigned short* __restrict__ Bh, const unsigned short* __restrict__ Bl,
    const float* __restrict__ pb0, const float* __restrict__ pw1,
    const float* __restrict__ pb1, float* __restrict__ outp)
{
    __shared__ __align__(16) short lds[4][128][32];   // 32 KB
    __shared__ float scratch[2][128][4];              // 4 KB

    const int tid = threadIdx.x;
    const int w   = tid >> 6;
    const int l   = tid & 63;
    const int l16 = l & 15;
    const int lq  = l >> 4;
    const int bm  = blockIdx.x * 128;
    const int wm  = (w & 1) * 64;
    const int wn  = (w >> 1) * 64;

    const int jrow = l >> 2;
    const int jkc  = l & 3;
    const int t0 = w * 2, t1 = t0 + 1;
    const int r0 = t0 * 16 + jrow, r1 = t1 * 16 + jrow;

    const size_t arow0 = (size_t)(bm + r0) * BOT + jkc * 8;
    const size_t arow1 = (size_t)(bm + r1) * BOT + jkc * 8;
    short* d00 = &lds[0][0][0] + t0 * 512;
    short* d01 = &lds[1][0][0] + t0 * 512;
    short* d02 = &lds[2][0][0] + t0 * 512;
    short* d03 = &lds[3][0][0] + t0 * 512;
    short* d10 = &lds[0][0][0] + t1 * 512;
    short* d11 = &lds[1][0][0] + t1 * 512;
    short* d12 = &lds[2][0][0] + t1 * 512;
    short* d13 = &lds[3][0][0] + t1 * 512;

    for (int nh = 0; nh < 2; ++nh) {
        const size_t brow0 = (size_t)(nh * 128 + r0) * BOT + jkc * 8;
        const size_t brow1 = (size_t)(nh * 128 + r1) * BOT + jkc * 8;

        f32x4 acc[4][4];
        #pragma unroll
        for (int i = 0; i < 4; ++i)
            #pragma unroll
            for (int j = 0; j < 4; ++j)
                acc[i][j] = (f32x4){0.f, 0.f, 0.f, 0.f};

        for (int k0 = 0; k0 < BOT; k0 += 32) {
            stage16(Ah + arow0 + k0, d00);
            stage16(Al + arow0 + k0, d01);
            stage16(Bh + brow0 + k0, d02);
            stage16(Bl + brow0 + k0, d03);
            stage16(Ah + arow1 + k0, d10);
            stage16(Al + arow1 + k0, d11);
            stage16(Bh + brow1 + k0, d12);
            stage16(Bl + brow1 + k0, d13);
            __syncthreads();

            bf16x8 ah[4], al[4], bh[4], bl[4];
            #pragma unroll
            for (int i = 0; i < 4; ++i) {
                ah[i] = *(const bf16x8*)&lds[0][wm + i*16 + l16][lq*8];
                al[i] = *(const bf16x8*)&lds[1][wm + i*16 + l16][lq*8];
                bh[i] = *(const bf16x8*)&lds[2][wn + i*16 + l16][lq*8];
                bl[i] = *(const bf16x8*)&lds[3][wn + i*16 + l16][lq*8];
            }
            #pragma unroll
            for (int i = 0; i < 4; ++i)
                #pragma unroll
                for (int j = 0; j < 4; ++j) {
                    acc[i][j] = __builtin_amdgcn_mfma_f32_16x16x32_bf16(ah[i], bh[j], acc[i][j], 0, 0, 0);
                    acc[i][j] = __builtin_amdgcn_mfma_f32_16x16x32_bf16(ah[i], bl[j], acc[i][j], 0, 0, 0);
                    acc[i][j] = __builtin_amdgcn_mfma_f32_16x16x32_bf16(al[i], bh[j], acc[i][j], 0, 0, 0);
                }
            __syncthreads();
        }

        // epilogue: g = gelu(acc + pb0), contract with pw1 (256x4) in-register
        float po[4][4][4];
        #pragma unroll
        for (int i = 0; i < 4; ++i)
            #pragma unroll
            for (int r = 0; r < 4; ++r)
                #pragma unroll
                for (int o = 0; o < 4; ++o)
                    po[i][r][o] = 0.f;

        #pragma unroll
        for (int j = 0; j < 4; ++j) {
            const int col = nh * 128 + wn + j * 16 + l16;
            const float bv = pb0[col];
            const float4 w1v = *(const float4*)&pw1[col * 4];
            #pragma unroll
            for (int i = 0; i < 4; ++i)
                #pragma unroll
                for (int r = 0; r < 4; ++r) {
                    const float g = gelu_f(acc[i][j][r] + bv);
                    po[i][r][0] = fmaf(g, w1v.x, po[i][r][0]);
                    po[i][r][1] = fmaf(g, w1v.y, po[i][r][1]);
                    po[i][r][2] = fmaf(g, w1v.z, po[i][r][2]);
                    po[i][r][3] = fmaf(g, w1v.w, po[i][r][3]);
                }
        }
        // reduce over the 16 lanes sharing lq (rows identical, cols differ)
        #pragma unroll
        for (int i = 0; i < 4; ++i)
            #pragma unroll
            for (int r = 0; r < 4; ++r)
                #pragma unroll
                for (int o = 0; o < 4; ++o) {
                    float v = po[i][r][o];
                    v += __shfl_xor(v, 1, 64);
                    v += __shfl_xor(v, 2, 64);
                    v += __shfl_xor(v, 4, 64);
                    v += __shfl_xor(v, 8, 64);
                    po[i][r][o] = v;
                }
        if (l16 == 0) {
            #pragma unroll
            for (int i = 0; i < 4; ++i)
                #pragma unroll
                for (int r = 0; r < 4; ++r) {
                    const int row = wm + i * 16 + lq * 4 + r;
                    #pragma unroll
                    for (int o = 0; o < 4; ++o) {
                        if (nh == 0) scratch[w >> 1][row][o]  = po[i][r][o];
                        else         scratch[w >> 1][row][o] += po[i][r][o];
                    }
                }
        }
    }

    __syncthreads();
    if (tid < 128) {
        float4 o;
        o.x = scratch[0][tid][0] + scratch[1][tid][0] + pb1[0];
        o.y = scratch[0][tid][1] + scratch[1][tid][1] + pb1[1];
        o.z = scratch[0][tid][2] + scratch[1][tid][2] + pb1[2];
        o.w = scratch[0][tid][3] + scratch[1][tid][3] + pb1[3];
        *(float4*)&outp[(size_t)(bm + tid) * 4] = o;
    }
}

// ---------------------------------------------------------------------------
// FUSED edge MLP (R2-exact, best measured: 788 us, no spill, VGPR 124).
// 64-edge tiles, 256 threads (4 waves), 64 KB LDS -> 2 blocks/CU.
//   h0 = gelu(x[gidx] @ W0a + Z[qidx])   (512 cols in 4 chunks of 128)
//   h1 = gelu(h0 @ W1 + b1)              (256, register-resident)
//   h2 = h1 @ W2 + b2                    (128, fp32 -> global)
// All operands LDS-staged via global_load_lds (the register-free prefetch:
// R8 proved B-from-global cannot pipeline within the ~250-reg budget).
// ---------------------------------------------------------------------------
__global__ __launch_bounds__(256, 2) void fused_edge(
    const unsigned short* __restrict__ xHg, const unsigned short* __restrict__ xLg,
    const unsigned short* __restrict__ w0aHg, const unsigned short* __restrict__ w0aLg,
    const unsigned short* __restrict__ w1Hg, const unsigned short* __restrict__ w1Lg,
    const unsigned short* __restrict__ w2Hg, const unsigned short* __restrict__ w2Lg,
    const float* __restrict__ Zg, const float* __restrict__ b1g,
    const float* __restrict__ b2g, const int* __restrict__ gp,
    float* __restrict__ h2g)
{
    extern __shared__ __align__(16) short smem[];
    short* stg = smem;                 // 16384 shorts = 32 KB staging / lbuf
    short* h0h = smem + 16384;         // [64][128] = 16 KB
    short* h0l = smem + 24576;         // 16 KB

    const int tid = threadIdx.x;
    const int w   = tid >> 6;
    const int l   = tid & 63;
    const int l16 = l & 15;
    const int lq  = l >> 4;
    const int bm  = blockIdx.x * 64;

    const int wn_p = w * 32;   // phase-1 / h2 col base
    const int wn1  = w * 64;   // h1 col base (0..255)

    // staging roles: thread covers row rx, 16B unit ux -> dst = base + tid*16B
    const int rx = tid >> 2;
    const int ux = tid & 3;
    const size_t xoff = (size_t)gp[2 * (bm + rx) + 1] * IN_DIM + ux * 8;
    const int q_e = gp[2 * (bm + l)];
    float* lbuf = ((float*)stg) + w * 2048;   // [64][32] f32 per wave

    short* stgAh  = stg;            // [64][32]
    short* stgAl  = stg + 2048;
    short* stgBh  = stg + 4096;     // [128][32]
    short* stgBl  = stg + 8192;
    short* stgW1h = stg;            // [256][32]
    short* stgW1l = stg + 8192;
    short* stgW2h = stg;            // [128][32]
    short* stgW2l = stg + 4096;

    f32x4 h1acc[4][4];
    #pragma unroll
    for (int i = 0; i < 4; ++i)
        #pragma unroll
        for (int j = 0; j < 4; ++j)
            h1acc[i][j] = (f32x4){0.f, 0.f, 0.f, 0.f};

    for (int c = 0; c < 4; ++c) {
        f32x4 acc1[4][2];
        #pragma unroll
        for (int i = 0; i < 4; ++i)
            #pragma unroll
            for (int j = 0; j < 2; ++j)
                acc1[i][j] = (f32x4){0.f, 0.f, 0.f, 0.f};

        // ---- phase 1: h0c[64][128] = x[gidx] @ W0a_c, K=256 ----
        {
            const size_t wo = (size_t)(c * 128 + rx) * IN_DIM + ux * 8;
            stage16(xHg + xoff, stgAh + tid * 8);
            stage16(xLg + xoff, stgAl + tid * 8);
            stage16(w0aHg + wo,                      stgBh + tid * 8);
            stage16(w0aLg + wo,                      stgBl + tid * 8);
            stage16(w0aHg + wo + (size_t)64 * IN_DIM, stgBh + 2048 + tid * 8);
            stage16(w0aLg + wo + (size_t)64 * IN_DIM, stgBl + 2048 + tid * 8);
        }
        __syncthreads();
        for (int ks = 0; ks < 8; ++ks) {
            bf16x8 ah[4], al[4], bh[2], bl[2];
            #pragma unroll
            for (int i = 0; i < 4; ++i) {
                const int ro = (i * 16 + l16) * 32 + lq * 8;
                ah[i] = *(const bf16x8*)&stgAh[ro];
                al[i] = *(const bf16x8*)&stgAl[ro];
            }
            #pragma unroll
            for (int j = 0; j < 2; ++j) {
                const int ro = (wn_p + j * 16 + l16) * 32 + lq * 8;
                bh[j] = *(const bf16x8*)&stgBh[ro];
                bl[j] = *(const bf16x8*)&stgBl[ro];
            }
            __syncthreads();
            if (ks < 7) {
                const int ko = (ks + 1) * 32;
                const size_t wo = (size_t)(c * 128 + rx) * IN_DIM + ko + ux * 8;
                stage16(xHg + xoff + ko, stgAh + tid * 8);
                stage16(xLg + xoff + ko, stgAl + tid * 8);
                stage16(w0aHg + wo,                      stgBh + tid * 8);
                stage16(w0aLg + wo,                      stgBl + tid * 8);
                stage16(w0aHg + wo + (size_t)64 * IN_DIM, stgBh + 2048 + tid * 8);
                stage16(w0aLg + wo + (size_t)64 * IN_DIM, stgBl + 2048 + tid * 8);
            }
            #pragma unroll
            for (int i = 0; i < 4; ++i)
                #pragma unroll
                for (int j = 0; j < 2; ++j) {
                    acc1[i][j] = __builtin_amdgcn_mfma_f32_16x16x32_bf16(ah[i], bh[j], acc1[i][j], 0, 0, 0);
                    acc1[i][j] = __builtin_amdgcn_mfma_f32_16x16x32_bf16(ah[i], bl[j], acc1[i][j], 0, 0, 0);
                    acc1[i][j] = __builtin_amdgcn_mfma_f32_16x16x32_bf16(al[i], bh[j], acc1[i][j], 0, 0, 0);
                }
            __syncthreads();
        }

        // ---- epilogue: +Z, gelu, cvt -> h0h/h0l (swizzled) ----
        #pragma unroll
        for (int j = 0; j < 2; ++j)
            #pragma unroll
            for (int i = 0; i < 4; ++i)
                #pragma unroll
                for (int r = 0; r < 4; ++r) {
                    const int rowq = i * 16 + lq * 4 + r;
                    const int u = j * 4 + (l16 >> 2);
                    lbuf[rowq * 32 + (((u ^ (rowq & 7)) << 2) | (l16 & 3))] = acc1[i][j][r];
                }
        __syncthreads();
        {
            const float* zrow = Zg + (size_t)q_e * H0_DIM + c * 128 + wn_p;
            #pragma unroll
            for (int g = 0; g < 2; ++g) {
                unsigned int hw[8], lw[8];
                #pragma unroll
                for (int c2 = 0; c2 < 4; ++c2) {
                    const int cq = g * 4 + c2;
                    float4 v = *(const float4*)&lbuf[l * 32 + ((cq ^ (l & 7)) << 2)];
                    const float4 z = *(const float4*)&zrow[cq * 4];
                    v.x = gelu_f(v.x + z.x); v.y = gelu_f(v.y + z.y);
                    v.z = gelu_f(v.z + z.z); v.w = gelu_f(v.w + z.w);
                    cvt4(v, &hw[c2 * 2], &lw[c2 * 2]);
                }
                const int u0 = (wn_p >> 3) + g * 2;
                const int o0 = l * 128 + (((u0    ) ^ (l & 7)) << 3);
                const int o1 = l * 128 + (((u0 + 1) ^ (l & 7)) << 3);
                uint4 H0, H1, L0, L1;
                H0.x = hw[0]; H0.y = hw[1]; H0.z = hw[2]; H0.w = hw[3];
                H1.x = hw[4]; H1.y = hw[5]; H1.z = hw[6]; H1.w = hw[7];
                L0.x = lw[0]; L0.y = lw[1]; L0.z = lw[2]; L0.w = lw[3];
                L1.x = lw[4]; L1.y = lw[5]; L1.z = lw[6]; L1.w = lw[7];
                *(uint4*)&h0h[o0] = H0; *(uint4*)&h0h[o1] = H1;
                *(uint4*)&h0l[o0] = L0; *(uint4*)&h0l[o1] = L1;
            }
        }
        __syncthreads();

        // ---- h1 partial: h1acc += h0c @ W1[:, c-block of K], K=128 ----
        {
            #pragma unroll
            for (int p = 0; p < 4; ++p) {
                const size_t o = (size_t)(rx + 64 * p) * H0_DIM + c * 128 + ux * 8;
                stage16(w1Hg + o, stgW1h + p * 2048 + tid * 8);
                stage16(w1Lg + o, stgW1l + p * 2048 + tid * 8);
            }
        }
        __syncthreads();
        for (int ks = 0; ks < 4; ++ks) {
            bf16x8 ah[4], al[4], bh[4], bl[4];
            #pragma unroll
            for (int i = 0; i < 4; ++i) {
                const int row = i * 16 + l16;
                const int uo = ((ks * 4 + lq) ^ (row & 7)) << 3;
                ah[i] = *(const bf16x8*)&h0h[row * 128 + uo];
                al[i] = *(const bf16x8*)&h0l[row * 128 + uo];
            }
            #pragma unroll
            for (int j = 0; j < 4; ++j) {
                const int ro = (wn1 + j * 16 + l16) * 32 + lq * 8;
                bh[j] = *(const bf16x8*)&stgW1h[ro];
                bl[j] = *(const bf16x8*)&stgW1l[ro];
            }
            __syncthreads();
            if (ks < 3) {
                #pragma unroll
                for (int p = 0; p < 4; ++p) {
                    const size_t o = (size_t)(rx + 64 * p) * H0_DIM + c * 128 + (ks + 1) * 32 + ux * 8;
                    stage16(w1Hg + o, stgW1h + p * 2048 + tid * 8);
                    stage16(w1Lg + o, stgW1l + p * 2048 + tid * 8);
                }
            }
            #pragma unroll
            for (int i = 0; i < 4; ++i)
                #pragma unroll
                for (int j = 0; j < 4; ++j) {
                    h1acc[i][j] = __builtin_amdgcn_mfma_f32_16x16x32_bf16(ah[i], bh[j], h1acc[i][j], 0, 0, 0);
                    h1acc[i][j] = __builtin_amdgcn_mfma_f32_16x16x32_bf16(ah[i], bl[j], h1acc[i][j], 0, 0, 0);
                    h1acc[i][j] = __builtin_amdgcn_mfma_f32_16x16x32_bf16(al[i], bh[j], h1acc[i][j], 0, 0, 0);
                }
            __syncthreads();
        }
    }

    // ---- h2 = gelu(h1 + b1) @ W2 + b2, K=256 in two 128-k halves ----
    f32x4 acc2[4][2];
    #pragma unroll
    for (int i = 0; i < 4; ++i)
        #pragma unroll
        for (int j = 0; j < 2; ++j)
            acc2[i][j] = (f32x4){0.f, 0.f, 0.f, 0.f};

    for (int kh = 0; kh < 2; ++kh) {
        const bool my = ((w >> 1) == kh);   // wave w owns h1 cols w*64..w*64+63
        #pragma unroll
        for (int j2 = 0; j2 < 2; ++j2) {
            if (my) {
                #pragma unroll
                for (int jj = 0; jj < 2; ++jj) {
                    const int j = j2 * 2 + jj;
                    const float bv = b1g[wn1 + j * 16 + l16];
                    #pragma unroll
                    for (int i = 0; i < 4; ++i)
                        #pragma unroll
                        for (int r = 0; r < 4; ++r) {
                            const int rowq = i * 16 + lq * 4 + r;
                            const int u = jj * 4 + (l16 >> 2);
                            lbuf[rowq * 32 + (((u ^ (rowq & 7)) << 2) | (l16 & 3))] =
                                gelu_f(h1acc[i][j][r] + bv);
                        }
                }
            }
            __syncthreads();
            if (my) {
                const int colb = (w & 1) * 64 + j2 * 32;
                #pragma unroll
                for (int g = 0; g < 2; ++g) {
                    unsigned int hw[8], lw[8];
                    #pragma unroll
                    for (int c2 = 0; c2 < 4; ++c2) {
                        const int cq = g * 4 + c2;
                        float4 v = *(const float4*)&lbuf[l * 32 + ((cq ^ (l & 7)) << 2)];
                        cvt4(v, &hw[c2 * 2], &lw[c2 * 2]);
                    }
                    const int u0 = ((colb + g * 16) >> 3);
                    const int o0 = l * 128 + (((u0    ) ^ (l & 7)) << 3);
                    const int o1 = l * 128 + (((u0 + 1) ^ (l & 7)) << 3);
                    uint4 H0, H1, L0, L1;
                    H0.x = hw[0]; H0.y = hw[1]; H0.z = hw[2]; H0.w = hw[3];
                    H1.x = hw[4]; H1.y = hw[5]; H1.z = hw[6]; H1.w = hw[7];
                    L0.x = lw[0]; L0.y = lw[1]; L0.z = lw[2]; L0.w = lw[3];
                    L1.x = lw[4]; L1.y = lw[5]; L1.z = lw[6]; L1.w = lw[7];
                    *(uint4*)&h0h[o0] = H0; *(uint4*)&h0h[o1] = H1;
                    *(uint4*)&h0l[o0] = L0; *(uint4*)&h0l[o1] = L1;
                }
            }
            __syncthreads();
        }

        // h2 partial K-loop (K=128): A = h1 half in h0 bufs, B = W2 staged
        {
            #pragma unroll
            for (int p = 0; p < 2; ++p) {
                const size_t o = (size_t)(rx + 64 * p) * H1_DIM + kh * 128 + ux * 8;
                stage16(w2Hg + o, stgW2h + p * 2048 + tid * 8);
                stage16(w2Lg + o, stgW2l + p * 2048 + tid * 8);
            }
        }
        __syncthreads();
        for (int ks = 0; ks < 4; ++ks) {
            bf16x8 ah[4], al[4], bh[2], bl[2];
            #pragma unroll
            for (int i = 0; i < 4; ++i) {
                const int row = i * 16 + l16;
                const int uo = ((ks * 4 + lq) ^ (row & 7)) << 3;
                ah[i] = *(const bf16x8*)&h0h[row * 128 + uo];
                al[i] = *(const bf16x8*)&h0l[row * 128 + uo];
            }
            #pragma unroll
            for (int j = 0; j < 2; ++j) {
                const int ro = (wn_p + j * 16 + l16) * 32 + lq * 8;
                bh[j] = *(const bf16x8*)&stgW2h[ro];
                bl[j] = *(const bf16x8*)&stgW2l[ro];
            }
            __syncthreads();
            if (ks < 3) {
                #pragma unroll
                for (int p = 0; p < 2; ++p) {
                    const size_t o = (size_t)(rx + 64 * p) * H1_DIM + kh * 128 + (ks + 1) * 32 + ux * 8;
                    stage16(w2Hg + o, stgW2h + p * 2048 + tid * 8);
                    stage16(w2Lg + o, stgW2l + p * 2048 + tid * 8);
                }
            }
            #pragma unroll
            for (int i = 0; i < 4; ++i)
                #pragma unroll
                for (int j = 0; j < 2; ++j) {
                    acc2[i][j] = __builtin_amdgcn_mfma_f32_16x16x32_bf16(ah[i], bh[j], acc2[i][j], 0, 0, 0);
                    acc2[i][j] = __builtin_amdgcn_mfma_f32_16x16x32_bf16(ah[i], bl[j], acc2[i][j], 0, 0, 0);
                    acc2[i][j] = __builtin_amdgcn_mfma_f32_16x16x32_bf16(al[i], bh[j], acc2[i][j], 0, 0, 0);
                }
            __syncthreads();
        }
    }

    // ---- h2 epilogue: + b2, fp32 store ----
    #pragma unroll
    for (int j = 0; j < 2; ++j) {
        const int n = wn_p + j * 16 + l16;
        const float bv = b2g[n];
        #pragma unroll
        for (int i = 0; i < 4; ++i) {
            const int er = bm + i * 16 + lq * 4;
            #pragma unroll
            for (int r = 0; r < 4; ++r)
                h2g[(size_t)(er + r) * BOT + n] = acc2[i][j][r] + bv;
        }
    }
}

// ---------------------------------------------------------------------------
// segment mean via precomputed offsets
// ---------------------------------------------------------------------------
__global__ __launch_bounds__(256) void seg_mean(
    const int* __restrict__ start, const float* __restrict__ h2,
    unsigned short* __restrict__ mH, unsigned short* __restrict__ mL)
{
    const int t = threadIdx.x;
    const int q = blockIdx.x * 8 + (t >> 5);
    const int quad = t & 31;
    const int s = start[q];
    const int e = start[q + 1];

    float4 acc = make_float4(0.f, 0.f, 0.f, 0.f);
    for (int i = s; i < e; ++i) {
        const float4 v = *(const float4*)&h2[(size_t)i * BOT + quad * 4];
        acc.x += v.x; acc.y += v.y; acc.z += v.z; acc.w += v.w;
    }
    const float inv = 1.0f / (float)((e - s) > 0 ? (e - s) : 1);
    float m0 = acc.x * inv, m1 = acc.y * inv, m2 = acc.z * inv, m3 = acc.w * inv;
    unsigned short h0 = f2bf(m0), h1 = f2bf(m1), h2s = f2bf(m2), h3 = f2bf(m3);
    uint2 H, L;
    H.x = pack2(h0, h1); H.y = pack2(h2s, h3);
    L.x = pack2(f2bf(m0 - bf2f(h0)), f2bf(m1 - bf2f(h1)));
    L.y = pack2(f2bf(m2 - bf2f(h2s)), f2bf(m3 - bf2f(h3)));
    *(uint2*)&mH[(size_t)q * BOT + quad * 4] = H;
    *(uint2*)&mL[(size_t)q * BOT + quad * 4] = L;
}

// ---------------------------------------------------------------------------
extern "C" void kernel_launch(void* const* d_in, const int* in_sizes, int n_in,
                              void* d_out, int out_size, void* d_ws, size_t ws_size,
                              hipStream_t stream)
{
    const float* x    = (const float*)d_in[0];
    const float* qpos = (const float*)d_in[1];
    const int*   edges= (const int*)  d_in[2];
    const float* w0   = (const float*)d_in[3];
    const float* b0   = (const float*)d_in[4];
    const float* w1   = (const float*)d_in[5];
    const float* b1   = (const float*)d_in[6];
    const float* w2   = (const float*)d_in[7];
    const float* b2   = (const float*)d_in[8];
    const float* pw0  = (const float*)d_in[9];
    const float* pb0  = (const float*)d_in[10];
    const float* pw1  = (const float*)d_in[11];
    const float* pb1  = (const float*)d_in[12];
    float* out = (float*)d_out;

    char* ws = (char*)d_ws;
    unsigned short* xH    = (unsigned short*)(ws + OFF_XH);
    unsigned short* xL    = (unsigned short*)(ws + OFF_XL);
    float*          Z     = (float*)(ws + OFF_Z);
    unsigned short* peH   = (unsigned short*)(ws + OFF_PEH);
    unsigned short* peL   = (unsigned short*)(ws + OFF_PEL);
    float*          h2    = (float*)(ws + OFF_H2);
    unsigned short* w0aH  = (unsigned short*)(ws + OFF_W0AH);
    unsigned short* w0aL  = (unsigned short*)(ws + OFF_W0AL);
    unsigned short* w0bH  = (unsigned short*)(ws + OFF_W0BH);
    unsigned short* w0bL  = (unsigned short*)(ws + OFF_W0BL);
    unsigned short* w1H   = (unsigned short*)(ws + OFF_W1H);
    unsigned short* w1L   = (unsigned short*)(ws + OFF_W1L);
    unsigned short* w2H   = (unsigned short*)(ws + OFF_W2H);
    unsigned short* w2L   = (unsigned short*)(ws + OFF_W2L);
    unsigned short* pw0H  = (unsigned short*)(ws + OFF_PW0H);
    unsigned short* pw0L  = (unsigned short*)(ws + OFF_PW0L);
    float*          bconst= (float*)(ws + OFF_BCONST);
    int*            start = (int*)(ws + OFF_START);
    unsigned short* meanH = (unsigned short*)(ws + OFF_MEANH);
    unsigned short* meanL = (unsigned short*)(ws + OFF_MEANL);

    // allow 64 KB dynamic LDS for the fused edge kernel (once per process)
    static bool attr_done = false;
    if (!attr_done) {
        hipFuncSetAttribute(reinterpret_cast<const void*>(&fused_edge),
                            hipFuncAttributeMaxDynamicSharedMemorySize, 65536);
        attr_done = true;
    }

    // one-time conversions
    conv_x<<<SEQ_/4, 256, 0, stream>>>(x, xH, xL);
    conv_w<<<(IN_DIM*H0_DIM + 255)/256, 256, 0, stream>>>(w0, w0aH, w0aL, IN_DIM, H0_DIM);
    conv_w<<<(PE_K*H0_DIM + 255)/256, 256, 0, stream>>>(w0 + (size_t)IN_DIM*H0_DIM, w0bH, w0bL, PE_K, H0_DIM);
    conv_w<<<(H0_DIM*H1_DIM + 255)/256, 256, 0, stream>>>(w1, w1H, w1L, H0_DIM, H1_DIM);
    conv_w<<<(H1_DIM*BOT + 255)/256, 256, 0, stream>>>(w2, w2H, w2L, H1_DIM, BOT);
    conv_w<<<(BOT*H1_DIM + 255)/256, 256, 0, stream>>>(pw0, pw0H, pw0L, BOT, H1_DIM);
    bias_fold<<<2, 256, 0, stream>>>(w0, b0, bconst);
    seg_offsets<<<(NE_ + 1 + 255)/256, 256, 0, stream>>>(edges, start);

    // Z = PE @ W0b' + bconst for all queries (4 L3-resident PE windows)
    for (int wn = 0; wn < NWIN; ++wn) {
        build_pe<<<QWIN/4, 256, 0, stream>>>(qpos, wn * QWIN, peH, peL);
        gemm_mfma<0><<<dim3(H0_DIM/128, QWIN/128), 256, 0, stream>>>(
            peH, peL, w0bH, w0bL, bconst, Z + (size_t)wn * QWIN * H0_DIM,
            QWIN, PE_K, H0_DIM);
    }

    // fused 3-layer edge MLP (R2-exact: 64-edge tiles, 2 blocks/CU)
    fused_edge<<<NE_/64, 256, 65536, stream>>>(
        xH, xL, w0aH, w0aL, w1H, w1L, w2H, w2L,
        Z, b1, b2, edges, h2);

    seg_mean<<<NQ_/8, 256, 0, stream>>>(start, h2, meanH, meanL);

    // fused pred0+pred1 (skips the g1 intermediate, 268 MB HBM saved)
    pred_fused<<<NQ_/128, 256, 0, stream>>>(
        meanH, meanL, pw0H, pw0L, pb0, pw1, pb1, out);
}

// Round 11
// 1573.058 us; speedup vs baseline: 1.5592x; 1.0024x over previous
//
#include <hip/hip_runtime.h>
#include <cmath>

// Problem constants
#define IN_DIM   256
#define H0_DIM   512
#define H1_DIM   256
#define BOT      128
#define NQ_      131072
#define NE_      262144
#define SEQ_     262144
#define PE_K     384          // PE cols 384..511 are constant -> folded into bias

// Workspace layout (bytes), ws = 1 GiB.
static const size_t OFF_XH    = 0;            // 262144*256*2 = 134217728
static const size_t OFF_XL    = 134217728;
static const size_t OFF_Z     = 268435456;    // 131072*512*4 = 268435456
static const size_t OFF_PEH   = 536870912;    // 131072*384*2 = 100663296 (full NQ)
static const size_t OFF_PEL   = 637534208;    // ends exactly at OFF_H2
static const size_t OFF_H2    = 738197504;    // 262144*128*4 = 134217728
static const size_t OFF_W0AH  = 872415232;    // [512][256] 262144
static const size_t OFF_W0AL  = 872677376;
static const size_t OFF_W0BH  = 872939520;    // [512][384] 393216
static const size_t OFF_W0BL  = 873332736;
static const size_t OFF_W1H   = 873725952;    // [256][512] 262144
static const size_t OFF_W1L   = 873988096;
static const size_t OFF_W2H   = 874250240;    // [128][256] 65536
static const size_t OFF_W2L   = 874315776;
static const size_t OFF_PW0H  = 874381312;    // [256][128] 65536
static const size_t OFF_PW0L  = 874446848;
static const size_t OFF_BCONST= 874512384;    // 512*4
static const size_t OFF_START = 874514432;    // (NQ+1)*4
// post-loop aliases
static const size_t OFF_MEANH = 0;            // alias xH (dead after fused edge kernel)
static const size_t OFF_MEANL = 33554432;

typedef __attribute__((ext_vector_type(8))) short bf16x8;
typedef __attribute__((ext_vector_type(4))) float f32x4;

__device__ __forceinline__ float gelu_f(float v) {
    return v * 0.5f * (1.0f + erff(v * 0.7071067811865476f));
}
__device__ __forceinline__ unsigned short f2bf(float f) {
    unsigned int u = __float_as_uint(f);
    unsigned int r = (u + 0x7FFFu + ((u >> 16) & 1u)) >> 16;
    return (unsigned short)r;
}
__device__ __forceinline__ float bf2f(unsigned short h) {
    return __uint_as_float(((unsigned int)h) << 16);
}
__device__ __forceinline__ unsigned int pack2(unsigned short a, unsigned short b) {
    return (unsigned int)a | ((unsigned int)b << 16);
}
__device__ __forceinline__ void stage16(const void* g, void* l) {
    __builtin_amdgcn_global_load_lds(
        (const __attribute__((address_space(1))) unsigned int*)g,
        (__attribute__((address_space(3))) unsigned int*)l,
        16, 0, 0);
}
// float4 -> 2x(hi pair) + 2x(lo pair)
__device__ __forceinline__ void cvt4(const float4 v, unsigned int* hw, unsigned int* lw) {
    const unsigned short a = f2bf(v.x), b = f2bf(v.y), c = f2bf(v.z), d = f2bf(v.w);
    hw[0] = pack2(a, b); hw[1] = pack2(c, d);
    lw[0] = pack2(f2bf(v.x - bf2f(a)), f2bf(v.y - bf2f(b)));
    lw[1] = pack2(f2bf(v.z - bf2f(c)), f2bf(v.w - bf2f(d)));
}

// ---------------------------------------------------------------------------
// x fp32 [SEQ][256] -> xH/xL bf16 (wave per row)
// ---------------------------------------------------------------------------
__global__ __launch_bounds__(256) void conv_x(
    const float* __restrict__ x,
    unsigned short* __restrict__ xH, unsigned short* __restrict__ xL)
{
    const int wv = threadIdx.x >> 6;
    const int l  = threadIdx.x & 63;
    const int row = blockIdx.x * 4 + wv;
    const size_t base = (size_t)row * IN_DIM + l * 4;
    float4 v = *(const float4*)&x[base];
    unsigned short h0 = f2bf(v.x), h1 = f2bf(v.y), h2 = f2bf(v.z), h3 = f2bf(v.w);
    uint2 H, L;
    H.x = pack2(h0, h1); H.y = pack2(h2, h3);
    L.x = pack2(f2bf(v.x - bf2f(h0)), f2bf(v.y - bf2f(h1)));
    L.y = pack2(f2bf(v.z - bf2f(h2)), f2bf(v.w - bf2f(h3)));
    *(uint2*)&xH[base] = H;
    *(uint2*)&xL[base] = L;
}

// ---------------------------------------------------------------------------
// Weight convert: W[K][N] fp32 -> WT hi/lo bf16 [N][K]
// ---------------------------------------------------------------------------
__global__ __launch_bounds__(256) void conv_w(
    const float* __restrict__ W, unsigned short* __restrict__ WTh,
    unsigned short* __restrict__ WTl, int K, int N)
{
    int idx = blockIdx.x * 256 + threadIdx.x;
    if (idx >= K * N) return;
    int k = idx / N, n = idx % N;
    float v = W[idx];
    unsigned short h = f2bf(v);
    WTh[(size_t)n * K + k] = h;
    WTl[(size_t)n * K + k] = f2bf(v - bf2f(h));
}

// ---------------------------------------------------------------------------
// bconst[n] = b0[n] + sum_j sin(om_j)*w0[640+j][n] + cos(om_j)*w0[704+j][n]
// ---------------------------------------------------------------------------
__global__ __launch_bounds__(256) void bias_fold(
    const float* __restrict__ w0, const float* __restrict__ b0,
    float* __restrict__ bconst)
{
    int n = blockIdx.x * 256 + threadIdx.x;
    if (n >= H0_DIM) return;
    float s = b0[n];
    for (int j = 0; j < 64; ++j) {
        float om = exp2f((float)j * (-13.287712379549449f / 64.0f));
        s += sinf(om) * w0[(size_t)(640 + j) * H0_DIM + n];
        s += cosf(om) * w0[(size_t)(704 + j) * H0_DIM + n];
    }
    bconst[n] = s;
}

// ---------------------------------------------------------------------------
// start[q] = first edge index with qidx >= q (qidx sorted ascending)
// ---------------------------------------------------------------------------
__global__ __launch_bounds__(256) void seg_offsets(
    const int* __restrict__ edges, int* __restrict__ start)
{
    int e = blockIdx.x * 256 + threadIdx.x;
    if (e > NE_) return;
    int qc = (e < NE_) ? edges[2 * e] : NQ_;
    int qp = (e > 0) ? edges[2 * e - 2] : -1;
    for (int q = qp + 1; q <= qc; ++q) start[q] = e;
}

// ---------------------------------------------------------------------------
// PE build, ALL queries in one dispatch: row q, cols 0..383.
// ---------------------------------------------------------------------------
__global__ __launch_bounds__(256) void build_pe(
    const float* __restrict__ qpos,
    unsigned short* __restrict__ peH, unsigned short* __restrict__ peL)
{
    const int wv = threadIdx.x >> 6;
    const int l  = threadIdx.x & 63;
    const int q  = blockIdx.x * 4 + wv;
    const int i0 = l * 8;
    if (i0 >= PE_K) return;
    const size_t base = (size_t)q * PE_K;

    const int cc = i0 >> 7;          // coord 0..2
    const int j0 = i0 & 127;
    const float cv = qpos[q * 3 + cc] * 0.01f - 1.0f;
    const bool is_sin = (j0 < 64);
    const int jj0 = j0 & 63;
    unsigned int hw[4], lw[4];
    #pragma unroll
    for (int p2 = 0; p2 < 4; ++p2) {
        unsigned short hh[2], ll[2];
        #pragma unroll
        for (int s = 0; s < 2; ++s) {
            int jj = jj0 + p2 * 2 + s;
            float om  = exp2f((float)jj * (-13.287712379549449f / 64.0f));
            float arg = cv * om;
            float v   = is_sin ? __sinf(arg) : __cosf(arg);
            unsigned short h = f2bf(v);
            hh[s] = h; ll[s] = f2bf(v - bf2f(h));
        }
        hw[p2] = pack2(hh[0], hh[1]);
        lw[p2] = pack2(ll[0], ll[1]);
    }
    uint4 H, L;
    H.x = hw[0]; H.y = hw[1]; H.z = hw[2]; H.w = hw[3];
    L.x = lw[0]; L.y = lw[1]; L.z = lw[2]; L.w = lw[3];
    *(uint4*)&peH[base + i0] = H;
    *(uint4*)&peL[base + i0] = L;
}

// ---------------------------------------------------------------------------
// Split-bf16 MFMA GEMM (3 passes AhBh+AhBl+AlBh). 128x128 tile, BK=32.
// R2-exact: A and B both LDS-staged (8x stage16/step), 2-barrier K-loop,
// static 32 KB LDS -> 3 blocks/CU. Single dispatch, M=NQ (4096 blocks:
// tail-wave waste amortized 4x vs the old 4x1024 window dispatches).
// Used for the Z build (PE @ W0b').
// ---------------------------------------------------------------------------
template <int ACT>
__global__ __launch_bounds__(256) void gemm_mfma(
    const unsigned short* __restrict__ Ah, const unsigned short* __restrict__ Al,
    const unsigned short* __restrict__ Bh, const unsigned short* __restrict__ Bl,
    const float* __restrict__ bias, float* __restrict__ Cf,
    int M, int K, int N)
{
    __shared__ __align__(16) short lds[4][128][32];   // 32 KB

    const int tid = threadIdx.x;
    const int w   = tid >> 6;
    const int l   = tid & 63;
    const int l16 = l & 15;
    const int lq  = l >> 4;
    const int bm  = blockIdx.y * 128;
    const int bn  = blockIdx.x * 128;
    const int wm  = (w & 1) * 64;
    const int wn  = (w >> 1) * 64;

    f32x4 acc[4][4];
    #pragma unroll
    for (int i = 0; i < 4; ++i)
        #pragma unroll
        for (int j = 0; j < 4; ++j)
            acc[i][j] = (f32x4){0.f, 0.f, 0.f, 0.f};

    const int jrow = l >> 2;
    const int jkc  = l & 3;
    const int t0 = w * 2, t1 = t0 + 1;
    const int r0 = t0 * 16 + jrow, r1 = t1 * 16 + jrow;

    const size_t arow0 = (size_t)(bm + r0) * K;
    const size_t arow1 = (size_t)(bm + r1) * K;
    const size_t brow0 = (size_t)(bn + r0) * K;
    const size_t brow1 = (size_t)(bn + r1) * K;
    short* d00 = &lds[0][0][0] + t0 * 512;
    short* d01 = &lds[1][0][0] + t0 * 512;
    short* d02 = &lds[2][0][0] + t0 * 512;
    short* d03 = &lds[3][0][0] + t0 * 512;
    short* d10 = &lds[0][0][0] + t1 * 512;
    short* d11 = &lds[1][0][0] + t1 * 512;
    short* d12 = &lds[2][0][0] + t1 * 512;
    short* d13 = &lds[3][0][0] + t1 * 512;

    for (int k0 = 0; k0 < K; k0 += 32) {
        const int ko = k0 + jkc * 8;
        stage16(Ah + arow0 + ko, d00);
        stage16(Al + arow0 + ko, d01);
        stage16(Bh + brow0 + ko, d02);
        stage16(Bl + brow0 + ko, d03);
        stage16(Ah + arow1 + ko, d10);
        stage16(Al + arow1 + ko, d11);
        stage16(Bh + brow1 + ko, d12);
        stage16(Bl + brow1 + ko, d13);
        __syncthreads();

        bf16x8 ah[4], al[4], bh[4], bl[4];
        #pragma unroll
        for (int i = 0; i < 4; ++i) {
            ah[i] = *(const bf16x8*)&lds[0][wm + i*16 + l16][lq*8];
            al[i] = *(const bf16x8*)&lds[1][wm + i*16 + l16][lq*8];
            bh[i] = *(const bf16x8*)&lds[2][wn + i*16 + l16][lq*8];
            bl[i] = *(const bf16x8*)&lds[3][wn + i*16 + l16][lq*8];
        }
        #pragma unroll
        for (int i = 0; i < 4; ++i)
            #pragma unroll
            for (int j = 0; j < 4; ++j) {
                acc[i][j] = __builtin_amdgcn_mfma_f32_16x16x32_bf16(ah[i], bh[j], acc[i][j], 0, 0, 0);
                acc[i][j] = __builtin_amdgcn_mfma_f32_16x16x32_bf16(ah[i], bl[j], acc[i][j], 0, 0, 0);
                acc[i][j] = __builtin_amdgcn_mfma_f32_16x16x32_bf16(al[i], bh[j], acc[i][j], 0, 0, 0);
            }
        __syncthreads();
    }

    #pragma unroll
    for (int j = 0; j < 4; ++j) {
        int n = bn + wn + j * 16 + l16;
        float bv = bias[n];
        #pragma unroll
        for (int i = 0; i < 4; ++i) {
            int mrow = bm + wm + i * 16 + lq * 4;
            #pragma unroll
            for (int r = 0; r < 4; ++r) {
                float v = acc[i][j][r] + bv;
                if (ACT) v = gelu_f(v);
                Cf[(size_t)(mrow + r) * N + n] = v;
            }
        }
    }
}

// ---------------------------------------------------------------------------
// FUSED pred0+pred1: per 128-query block,
//   g = gelu(mean @ pw0 + pb0)  (N=256 in two 128-col halves, K=128)
//   out = g @ pw1 + pb1         (256 -> 4, contracted in the epilogue)
// Skips the g1 intermediate entirely (saves 268 MB HBM round-trip).
// ---------------------------------------------------------------------------
__global__ __launch_bounds__(256) void pred_fused(
    const unsigned short* __restrict__ Ah, const unsigned short* __restrict__ Al,
    const unsigned short* __restrict__ Bh, const unsigned short* __restrict__ Bl,
    const float* __restrict__ pb0, const float* __restrict__ pw1,
    const float* __restrict__ pb1, float* __restrict__ outp)
{
    __shared__ __align__(16) short lds[4][128][32];   // 32 KB
    __shared__ float scratch[2][128][4];              // 4 KB

    const int tid = threadIdx.x;
    const int w   = tid >> 6;
    const int l   = tid & 63;
    const int l16 = l & 15;
    const int lq  = l >> 4;
    const int bm  = blockIdx.x * 128;
    const int wm  = (w & 1) * 64;
    const int wn  = (w >> 1) * 64;

    const int jrow = l >> 2;
    const int jkc  = l & 3;
    const int t0 = w * 2, t1 = t0 + 1;
    const int r0 = t0 * 16 + jrow, r1 = t1 * 16 + jrow;

    const size_t arow0 = (size_t)(bm + r0) * BOT + jkc * 8;
    const size_t arow1 = (size_t)(bm + r1) * BOT + jkc * 8;
    short* d00 = &lds[0][0][0] + t0 * 512;
    short* d01 = &lds[1][0][0] + t0 * 512;
    short* d02 = &lds[2][0][0] + t0 * 512;
    short* d03 = &lds[3][0][0] + t0 * 512;
    short* d10 = &lds[0][0][0] + t1 * 512;
    short* d11 = &lds[1][0][0] + t1 * 512;
    short* d12 = &lds[2][0][0] + t1 * 512;
    short* d13 = &lds[3][0][0] + t1 * 512;

    for (int nh = 0; nh < 2; ++nh) {
        const size_t brow0 = (size_t)(nh * 128 + r0) * BOT + jkc * 8;
        const size_t brow1 = (size_t)(nh * 128 + r1) * BOT + jkc * 8;

        f32x4 acc[4][4];
        #pragma unroll
        for (int i = 0; i < 4; ++i)
            #pragma unroll
            for (int j = 0; j < 4; ++j)
                acc[i][j] = (f32x4){0.f, 0.f, 0.f, 0.f};

        for (int k0 = 0; k0 < BOT; k0 += 32) {
            stage16(Ah + arow0 + k0, d00);
            stage16(Al + arow0 + k0, d01);
            stage16(Bh + brow0 + k0, d02);
            stage16(Bl + brow0 + k0, d03);
            stage16(Ah + arow1 + k0, d10);
            stage16(Al + arow1 + k0, d11);
            stage16(Bh + brow1 + k0, d12);
            stage16(Bl + brow1 + k0, d13);
            __syncthreads();

            bf16x8 ah[4], al[4], bh[4], bl[4];
            #pragma unroll
            for (int i = 0; i < 4; ++i) {
                ah[i] = *(const bf16x8*)&lds[0][wm + i*16 + l16][lq*8];
                al[i] = *(const bf16x8*)&lds[1][wm + i*16 + l16][lq*8];
                bh[i] = *(const bf16x8*)&lds[2][wn + i*16 + l16][lq*8];
                bl[i] = *(const bf16x8*)&lds[3][wn + i*16 + l16][lq*8];
            }
            #pragma unroll
            for (int i = 0; i < 4; ++i)
                #pragma unroll
                for (int j = 0; j < 4; ++j) {
                    acc[i][j] = __builtin_amdgcn_mfma_f32_16x16x32_bf16(ah[i], bh[j], acc[i][j], 0, 0, 0);
                    acc[i][j] = __builtin_amdgcn_mfma_f32_16x16x32_bf16(ah[i], bl[j], acc[i][j], 0, 0, 0);
                    acc[i][j] = __builtin_amdgcn_mfma_f32_16x16x32_bf16(al[i], bh[j], acc[i][j], 0, 0, 0);
                }
            __syncthreads();
        }

        // epilogue: g = gelu(acc + pb0), contract with pw1 (256x4) in-register
        float po[4][4][4];
        #pragma unroll
        for (int i = 0; i < 4; ++i)
            #pragma unroll
            for (int r = 0; r < 4; ++r)
                #pragma unroll
                for (int o = 0; o < 4; ++o)
                    po[i][r][o] = 0.f;

        #pragma unroll
        for (int j = 0; j < 4; ++j) {
            const int col = nh * 128 + wn + j * 16 + l16;
            const float bv = pb0[col];
            const float4 w1v = *(const float4*)&pw1[col * 4];
            #pragma unroll
            for (int i = 0; i < 4; ++i)
                #pragma unroll
                for (int r = 0; r < 4; ++r) {
                    const float g = gelu_f(acc[i][j][r] + bv);
                    po[i][r][0] = fmaf(g, w1v.x, po[i][r][0]);
                    po[i][r][1] = fmaf(g, w1v.y, po[i][r][1]);
                    po[i][r][2] = fmaf(g, w1v.z, po[i][r][2]);
                    po[i][r][3] = fmaf(g, w1v.w, po[i][r][3]);
                }
        }
        // reduce over the 16 lanes sharing lq (rows identical, cols differ)
        #pragma unroll
        for (int i = 0; i < 4; ++i)
            #pragma unroll
            for (int r = 0; r < 4; ++r)
                #pragma unroll
                for (int o = 0; o < 4; ++o) {
                    float v = po[i][r][o];
                    v += __shfl_xor(v, 1, 64);
                    v += __shfl_xor(v, 2, 64);
                    v += __shfl_xor(v, 4, 64);
                    v += __shfl_xor(v, 8, 64);
                    po[i][r][o] = v;
                }
        if (l16 == 0) {
            #pragma unroll
            for (int i = 0; i < 4; ++i)
                #pragma unroll
                for (int r = 0; r < 4; ++r) {
                    const int row = wm + i * 16 + lq * 4 + r;
                    #pragma unroll
                    for (int o = 0; o < 4; ++o) {
                        if (nh == 0) scratch[w >> 1][row][o]  = po[i][r][o];
                        else         scratch[w >> 1][row][o] += po[i][r][o];
                    }
                }
        }
    }

    __syncthreads();
    if (tid < 128) {
        float4 o;
        o.x = scratch[0][tid][0] + scratch[1][tid][0] + pb1[0];
        o.y = scratch[0][tid][1] + scratch[1][tid][1] + pb1[1];
        o.z = scratch[0][tid][2] + scratch[1][tid][2] + pb1[2];
        o.w = scratch[0][tid][3] + scratch[1][tid][3] + pb1[3];
        *(float4*)&outp[(size_t)(bm + tid) * 4] = o;
    }
}

// ---------------------------------------------------------------------------
// FUSED edge MLP (R2-exact, best measured: 788 us, no spill, VGPR 124).
// 64-edge tiles, 256 threads (4 waves), 64 KB LDS -> 2 blocks/CU.
//   h0 = gelu(x[gidx] @ W0a + Z[qidx])   (512 cols in 4 chunks of 128)
//   h1 = gelu(h0 @ W1 + b1)              (256, register-resident)
//   h2 = h1 @ W2 + b2                    (128, fp32 -> global)
// All operands LDS-staged via global_load_lds (the register-free prefetch:
// R8 proved B-from-global cannot pipeline within the ~250-reg budget).
// ---------------------------------------------------------------------------
__global__ __launch_bounds__(256, 2) void fused_edge(
    const unsigned short* __restrict__ xHg, const unsigned short* __restrict__ xLg,
    const unsigned short* __restrict__ w0aHg, const unsigned short* __restrict__ w0aLg,
    const unsigned short* __restrict__ w1Hg, const unsigned short* __restrict__ w1Lg,
    const unsigned short* __restrict__ w2Hg, const unsigned short* __restrict__ w2Lg,
    const float* __restrict__ Zg, const float* __restrict__ b1g,
    const float* __restrict__ b2g, const int* __restrict__ gp,
    float* __restrict__ h2g)
{
    extern __shared__ __align__(16) short smem[];
    short* stg = smem;                 // 16384 shorts = 32 KB staging / lbuf
    short* h0h = smem + 16384;         // [64][128] = 16 KB
    short* h0l = smem + 24576;         // 16 KB

    const int tid = threadIdx.x;
    const int w   = tid >> 6;
    const int l   = tid & 63;
    const int l16 = l & 15;
    const int lq  = l >> 4;
    const int bm  = blockIdx.x * 64;

    const int wn_p = w * 32;   // phase-1 / h2 col base
    const int wn1  = w * 64;   // h1 col base (0..255)

    // staging roles: thread covers row rx, 16B unit ux -> dst = base + tid*16B
    const int rx = tid >> 2;
    const int ux = tid & 3;
    const size_t xoff = (size_t)gp[2 * (bm + rx) + 1] * IN_DIM + ux * 8;
    const int q_e = gp[2 * (bm + l)];
    float* lbuf = ((float*)stg) + w * 2048;   // [64][32] f32 per wave

    short* stgAh  = stg;            // [64][32]
    short* stgAl  = stg + 2048;
    short* stgBh  = stg + 4096;     // [128][32]
    short* stgBl  = stg + 8192;
    short* stgW1h = stg;            // [256][32]
    short* stgW1l = stg + 8192;
    short* stgW2h = stg;            // [128][32]
    short* stgW2l = stg + 4096;

    f32x4 h1acc[4][4];
    #pragma unroll
    for (int i = 0; i < 4; ++i)
        #pragma unroll
        for (int j = 0; j < 4; ++j)
            h1acc[i][j] = (f32x4){0.f, 0.f, 0.f, 0.f};

    for (int c = 0; c < 4; ++c) {
        f32x4 acc1[4][2];
        #pragma unroll
        for (int i = 0; i < 4; ++i)
            #pragma unroll
            for (int j = 0; j < 2; ++j)
                acc1[i][j] = (f32x4){0.f, 0.f, 0.f, 0.f};

        // ---- phase 1: h0c[64][128] = x[gidx] @ W0a_c, K=256 ----
        {
            const size_t wo = (size_t)(c * 128 + rx) * IN_DIM + ux * 8;
            stage16(xHg + xoff, stgAh + tid * 8);
            stage16(xLg + xoff, stgAl + tid * 8);
            stage16(w0aHg + wo,                      stgBh + tid * 8);
            stage16(w0aLg + wo,                      stgBl + tid * 8);
            stage16(w0aHg + wo + (size_t)64 * IN_DIM, stgBh + 2048 + tid * 8);
            stage16(w0aLg + wo + (size_t)64 * IN_DIM, stgBl + 2048 + tid * 8);
        }
        __syncthreads();
        for (int ks = 0; ks < 8; ++ks) {
            bf16x8 ah[4], al[4], bh[2], bl[2];
            #pragma unroll
            for (int i = 0; i < 4; ++i) {
                const int ro = (i * 16 + l16) * 32 + lq * 8;
                ah[i] = *(const bf16x8*)&stgAh[ro];
                al[i] = *(const bf16x8*)&stgAl[ro];
            }
            #pragma unroll
            for (int j = 0; j < 2; ++j) {
                const int ro = (wn_p + j * 16 + l16) * 32 + lq * 8;
                bh[j] = *(const bf16x8*)&stgBh[ro];
                bl[j] = *(const bf16x8*)&stgBl[ro];
            }
            __syncthreads();
            if (ks < 7) {
                const int ko = (ks + 1) * 32;
                const size_t wo = (size_t)(c * 128 + rx) * IN_DIM + ko + ux * 8;
                stage16(xHg + xoff + ko, stgAh + tid * 8);
                stage16(xLg + xoff + ko, stgAl + tid * 8);
                stage16(w0aHg + wo,                      stgBh + tid * 8);
                stage16(w0aLg + wo,                      stgBl + tid * 8);
                stage16(w0aHg + wo + (size_t)64 * IN_DIM, stgBh + 2048 + tid * 8);
                stage16(w0aLg + wo + (size_t)64 * IN_DIM, stgBl + 2048 + tid * 8);
            }
            #pragma unroll
            for (int i = 0; i < 4; ++i)
                #pragma unroll
                for (int j = 0; j < 2; ++j) {
                    acc1[i][j] = __builtin_amdgcn_mfma_f32_16x16x32_bf16(ah[i], bh[j], acc1[i][j], 0, 0, 0);
                    acc1[i][j] = __builtin_amdgcn_mfma_f32_16x16x32_bf16(ah[i], bl[j], acc1[i][j], 0, 0, 0);
                    acc1[i][j] = __builtin_amdgcn_mfma_f32_16x16x32_bf16(al[i], bh[j], acc1[i][j], 0, 0, 0);
                }
            __syncthreads();
        }

        // ---- epilogue: +Z, gelu, cvt -> h0h/h0l (swizzled) ----
        #pragma unroll
        for (int j = 0; j < 2; ++j)
            #pragma unroll
            for (int i = 0; i < 4; ++i)
                #pragma unroll
                for (int r = 0; r < 4; ++r) {
                    const int rowq = i * 16 + lq * 4 + r;
                    const int u = j * 4 + (l16 >> 2);
                    lbuf[rowq * 32 + (((u ^ (rowq & 7)) << 2) | (l16 & 3))] = acc1[i][j][r];
                }
        __syncthreads();
        {
            const float* zrow = Zg + (size_t)q_e * H0_DIM + c * 128 + wn_p;
            #pragma unroll
            for (int g = 0; g < 2; ++g) {
                unsigned int hw[8], lw[8];
                #pragma unroll
                for (int c2 = 0; c2 < 4; ++c2) {
                    const int cq = g * 4 + c2;
                    float4 v = *(const float4*)&lbuf[l * 32 + ((cq ^ (l & 7)) << 2)];
                    const float4 z = *(const float4*)&zrow[cq * 4];
                    v.x = gelu_f(v.x + z.x); v.y = gelu_f(v.y + z.y);
                    v.z = gelu_f(v.z + z.z); v.w = gelu_f(v.w + z.w);
                    cvt4(v, &hw[c2 * 2], &lw[c2 * 2]);
                }
                const int u0 = (wn_p >> 3) + g * 2;
                const int o0 = l * 128 + (((u0    ) ^ (l & 7)) << 3);
                const int o1 = l * 128 + (((u0 + 1) ^ (l & 7)) << 3);
                uint4 H0, H1, L0, L1;
                H0.x = hw[0]; H0.y = hw[1]; H0.z = hw[2]; H0.w = hw[3];
                H1.x = hw[4]; H1.y = hw[5]; H1.z = hw[6]; H1.w = hw[7];
                L0.x = lw[0]; L0.y = lw[1]; L0.z = lw[2]; L0.w = lw[3];
                L1.x = lw[4]; L1.y = lw[5]; L1.z = lw[6]; L1.w = lw[7];
                *(uint4*)&h0h[o0] = H0; *(uint4*)&h0h[o1] = H1;
                *(uint4*)&h0l[o0] = L0; *(uint4*)&h0l[o1] = L1;
            }
        }
        __syncthreads();

        // ---- h1 partial: h1acc += h0c @ W1[:, c-block of K], K=128 ----
        {
            #pragma unroll
            for (int p = 0; p < 4; ++p) {
                const size_t o = (size_t)(rx + 64 * p) * H0_DIM + c * 128 + ux * 8;
                stage16(w1Hg + o, stgW1h + p * 2048 + tid * 8);
                stage16(w1Lg + o, stgW1l + p * 2048 + tid * 8);
            }
        }
        __syncthreads();
        for (int ks = 0; ks < 4; ++ks) {
            bf16x8 ah[4], al[4], bh[4], bl[4];
            #pragma unroll
            for (int i = 0; i < 4; ++i) {
                const int row = i * 16 + l16;
                const int uo = ((ks * 4 + lq) ^ (row & 7)) << 3;
                ah[i] = *(const bf16x8*)&h0h[row * 128 + uo];
                al[i] = *(const bf16x8*)&h0l[row * 128 + uo];
            }
            #pragma unroll
            for (int j = 0; j < 4; ++j) {
                const int ro = (wn1 + j * 16 + l16) * 32 + lq * 8;
                bh[j] = *(const bf16x8*)&stgW1h[ro];
                bl[j] = *(const bf16x8*)&stgW1l[ro];
            }
            __syncthreads();
            if (ks < 3) {
                #pragma unroll
                for (int p = 0; p < 4; ++p) {
                    const size_t o = (size_t)(rx + 64 * p) * H0_DIM + c * 128 + (ks + 1) * 32 + ux * 8;
                    stage16(w1Hg + o, stgW1h + p * 2048 + tid * 8);
                    stage16(w1Lg + o, stgW1l + p * 2048 + tid * 8);
                }
            }
            #pragma unroll
            for (int i = 0; i < 4; ++i)
                #pragma unroll
                for (int j = 0; j < 4; ++j) {
                    h1acc[i][j] = __builtin_amdgcn_mfma_f32_16x16x32_bf16(ah[i], bh[j], h1acc[i][j], 0, 0, 0);
                    h1acc[i][j] = __builtin_amdgcn_mfma_f32_16x16x32_bf16(ah[i], bl[j], h1acc[i][j], 0, 0, 0);
                    h1acc[i][j] = __builtin_amdgcn_mfma_f32_16x16x32_bf16(al[i], bh[j], h1acc[i][j], 0, 0, 0);
                }
            __syncthreads();
        }
    }

    // ---- h2 = gelu(h1 + b1) @ W2 + b2, K=256 in two 128-k halves ----
    f32x4 acc2[4][2];
    #pragma unroll
    for (int i = 0; i < 4; ++i)
        #pragma unroll
        for (int j = 0; j < 2; ++j)
            acc2[i][j] = (f32x4){0.f, 0.f, 0.f, 0.f};

    for (int kh = 0; kh < 2; ++kh) {
        const bool my = ((w >> 1) == kh);   // wave w owns h1 cols w*64..w*64+63
        #pragma unroll
        for (int j2 = 0; j2 < 2; ++j2) {
            if (my) {
                #pragma unroll
                for (int jj = 0; jj < 2; ++jj) {
                    const int j = j2 * 2 + jj;
                    const float bv = b1g[wn1 + j * 16 + l16];
                    #pragma unroll
                    for (int i = 0; i < 4; ++i)
                        #pragma unroll
                        for (int r = 0; r < 4; ++r) {
                            const int rowq = i * 16 + lq * 4 + r;
                            const int u = jj * 4 + (l16 >> 2);
                            lbuf[rowq * 32 + (((u ^ (rowq & 7)) << 2) | (l16 & 3))] =
                                gelu_f(h1acc[i][j][r] + bv);
                        }
                }
            }
            __syncthreads();
            if (my) {
                const int colb = (w & 1) * 64 + j2 * 32;
                #pragma unroll
                for (int g = 0; g < 2; ++g) {
                    unsigned int hw[8], lw[8];
                    #pragma unroll
                    for (int c2 = 0; c2 < 4; ++c2) {
                        const int cq = g * 4 + c2;
                        float4 v = *(const float4*)&lbuf[l * 32 + ((cq ^ (l & 7)) << 2)];
                        cvt4(v, &hw[c2 * 2], &lw[c2 * 2]);
                    }
                    const int u0 = ((colb + g * 16) >> 3);
                    const int o0 = l * 128 + (((u0    ) ^ (l & 7)) << 3);
                    const int o1 = l * 128 + (((u0 + 1) ^ (l & 7)) << 3);
                    uint4 H0, H1, L0, L1;
                    H0.x = hw[0]; H0.y = hw[1]; H0.z = hw[2]; H0.w = hw[3];
                    H1.x = hw[4]; H1.y = hw[5]; H1.z = hw[6]; H1.w = hw[7];
                    L0.x = lw[0]; L0.y = lw[1]; L0.z = lw[2]; L0.w = lw[3];
                    L1.x = lw[4]; L1.y = lw[5]; L1.z = lw[6]; L1.w = lw[7];
                    *(uint4*)&h0h[o0] = H0; *(uint4*)&h0h[o1] = H1;
                    *(uint4*)&h0l[o0] = L0; *(uint4*)&h0l[o1] = L1;
                }
            }
            __syncthreads();
        }

        // h2 partial K-loop (K=128): A = h1 half in h0 bufs, B = W2 staged
        {
            #pragma unroll
            for (int p = 0; p < 2; ++p) {
                const size_t o = (size_t)(rx + 64 * p) * H1_DIM + kh * 128 + ux * 8;
                stage16(w2Hg + o, stgW2h + p * 2048 + tid * 8);
                stage16(w2Lg + o, stgW2l + p * 2048 + tid * 8);
            }
        }
        __syncthreads();
        for (int ks = 0; ks < 4; ++ks) {
            bf16x8 ah[4], al[4], bh[2], bl[2];
            #pragma unroll
            for (int i = 0; i < 4; ++i) {
                const int row = i * 16 + l16;
                const int uo = ((ks * 4 + lq) ^ (row & 7)) << 3;
                ah[i] = *(const bf16x8*)&h0h[row * 128 + uo];
                al[i] = *(const bf16x8*)&h0l[row * 128 + uo];
            }
            #pragma unroll
            for (int j = 0; j < 2; ++j) {
                const int ro = (wn_p + j * 16 + l16) * 32 + lq * 8;
                bh[j] = *(const bf16x8*)&stgW2h[ro];
                bl[j] = *(const bf16x8*)&stgW2l[ro];
            }
            __syncthreads();
            if (ks < 3) {
                #pragma unroll
                for (int p = 0; p < 2; ++p) {
                    const size_t o = (size_t)(rx + 64 * p) * H1_DIM + kh * 128 + (ks + 1) * 32 + ux * 8;
                    stage16(w2Hg + o, stgW2h + p * 2048 + tid * 8);
                    stage16(w2Lg + o, stgW2l + p * 2048 + tid * 8);
                }
            }
            #pragma unroll
            for (int i = 0; i < 4; ++i)
                #pragma unroll
                for (int j = 0; j < 2; ++j) {
                    acc2[i][j] = __builtin_amdgcn_mfma_f32_16x16x32_bf16(ah[i], bh[j], acc2[i][j], 0, 0, 0);
                    acc2[i][j] = __builtin_amdgcn_mfma_f32_16x16x32_bf16(ah[i], bl[j], acc2[i][j], 0, 0, 0);
                    acc2[i][j] = __builtin_amdgcn_mfma_f32_16x16x32_bf16(al[i], bh[j], acc2[i][j], 0, 0, 0);
                }
            __syncthreads();
        }
    }

    // ---- h2 epilogue: + b2, fp32 store ----
    #pragma unroll
    for (int j = 0; j < 2; ++j) {
        const int n = wn_p + j * 16 + l16;
        const float bv = b2g[n];
        #pragma unroll
        for (int i = 0; i < 4; ++i) {
            const int er = bm + i * 16 + lq * 4;
            #pragma unroll
            for (int r = 0; r < 4; ++r)
                h2g[(size_t)(er + r) * BOT + n] = acc2[i][j][r] + bv;
        }
    }
}

// ---------------------------------------------------------------------------
// segment mean via precomputed offsets
// ---------------------------------------------------------------------------
__global__ __launch_bounds__(256) void seg_mean(
    const int* __restrict__ start, const float* __restrict__ h2,
    unsigned short* __restrict__ mH, unsigned short* __restrict__ mL)
{
    const int t = threadIdx.x;
    const int q = blockIdx.x * 8 + (t >> 5);
    const int quad = t & 31;
    const int s = start[q];
    const int e = start[q + 1];

    float4 acc = make_float4(0.f, 0.f, 0.f, 0.f);
    for (int i = s; i < e; ++i) {
        const float4 v = *(const float4*)&h2[(size_t)i * BOT + quad * 4];
        acc.x += v.x; acc.y += v.y; acc.z += v.z; acc.w += v.w;
    }
    const float inv = 1.0f / (float)((e - s) > 0 ? (e - s) : 1);
    float m0 = acc.x * inv, m1 = acc.y * inv, m2 = acc.z * inv, m3 = acc.w * inv;
    unsigned short h0 = f2bf(m0), h1 = f2bf(m1), h2s = f2bf(m2), h3 = f2bf(m3);
    uint2 H, L;
    H.x = pack2(h0, h1); H.y = pack2(h2s, h3);
    L.x = pack2(f2bf(m0 - bf2f(h0)), f2bf(m1 - bf2f(h1)));
    L.y = pack2(f2bf(m2 - bf2f(h2s)), f2bf(m3 - bf2f(h3)));
    *(uint2*)&mH[(size_t)q * BOT + quad * 4] = H;
    *(uint2*)&mL[(size_t)q * BOT + quad * 4] = L;
}

// ---------------------------------------------------------------------------
extern "C" void kernel_launch(void* const* d_in, const int* in_sizes, int n_in,
                              void* d_out, int out_size, void* d_ws, size_t ws_size,
                              hipStream_t stream)
{
    const float* x    = (const float*)d_in[0];
    const float* qpos = (const float*)d_in[1];
    const int*   edges= (const int*)  d_in[2];
    const float* w0   = (const float*)d_in[3];
    const float* b0   = (const float*)d_in[4];
    const float* w1   = (const float*)d_in[5];
    const float* b1   = (const float*)d_in[6];
    const float* w2   = (const float*)d_in[7];
    const float* b2   = (const float*)d_in[8];
    const float* pw0  = (const float*)d_in[9];
    const float* pb0  = (const float*)d_in[10];
    const float* pw1  = (const float*)d_in[11];
    const float* pb1  = (const float*)d_in[12];
    float* out = (float*)d_out;

    char* ws = (char*)d_ws;
    unsigned short* xH    = (unsigned short*)(ws + OFF_XH);
    unsigned short* xL    = (unsigned short*)(ws + OFF_XL);
    float*          Z     = (float*)(ws + OFF_Z);
    unsigned short* peH   = (unsigned short*)(ws + OFF_PEH);
    unsigned short* peL   = (unsigned short*)(ws + OFF_PEL);
    float*          h2    = (float*)(ws + OFF_H2);
    unsigned short* w0aH  = (unsigned short*)(ws + OFF_W0AH);
    unsigned short* w0aL  = (unsigned short*)(ws + OFF_W0AL);
    unsigned short* w0bH  = (unsigned short*)(ws + OFF_W0BH);
    unsigned short* w0bL  = (unsigned short*)(ws + OFF_W0BL);
    unsigned short* w1H   = (unsigned short*)(ws + OFF_W1H);
    unsigned short* w1L   = (unsigned short*)(ws + OFF_W1L);
    unsigned short* w2H   = (unsigned short*)(ws + OFF_W2H);
    unsigned short* w2L   = (unsigned short*)(ws + OFF_W2L);
    unsigned short* pw0H  = (unsigned short*)(ws + OFF_PW0H);
    unsigned short* pw0L  = (unsigned short*)(ws + OFF_PW0L);
    float*          bconst= (float*)(ws + OFF_BCONST);
    int*            start = (int*)(ws + OFF_START);
    unsigned short* meanH = (unsigned short*)(ws + OFF_MEANH);
    unsigned short* meanL = (unsigned short*)(ws + OFF_MEANL);

    // allow 64 KB dynamic LDS for the fused edge kernel (once per process)
    static bool attr_done = false;
    if (!attr_done) {
        hipFuncSetAttribute(reinterpret_cast<const void*>(&fused_edge),
                            hipFuncAttributeMaxDynamicSharedMemorySize, 65536);
        attr_done = true;
    }

    // one-time conversions
    conv_x<<<SEQ_/4, 256, 0, stream>>>(x, xH, xL);
    conv_w<<<(IN_DIM*H0_DIM + 255)/256, 256, 0, stream>>>(w0, w0aH, w0aL, IN_DIM, H0_DIM);
    conv_w<<<(PE_K*H0_DIM + 255)/256, 256, 0, stream>>>(w0 + (size_t)IN_DIM*H0_DIM, w0bH, w0bL, PE_K, H0_DIM);
    conv_w<<<(H0_DIM*H1_DIM + 255)/256, 256, 0, stream>>>(w1, w1H, w1L, H0_DIM, H1_DIM);
    conv_w<<<(H1_DIM*BOT + 255)/256, 256, 0, stream>>>(w2, w2H, w2L, H1_DIM, BOT);
    conv_w<<<(BOT*H1_DIM + 255)/256, 256, 0, stream>>>(pw0, pw0H, pw0L, BOT, H1_DIM);
    bias_fold<<<2, 256, 0, stream>>>(w0, b0, bconst);
    seg_offsets<<<(NE_ + 1 + 255)/256, 256, 0, stream>>>(edges, start);

    // Z = PE @ W0b' + bconst: build full PE once, then ONE gemm dispatch
    // (4096 blocks; the old 4x1024-window form wasted ~3 extra partial
    // block-waves at 3 blocks/CU = 768 co-resident)
    build_pe<<<NQ_/4, 256, 0, stream>>>(qpos, peH, peL);
    gemm_mfma<0><<<dim3(H0_DIM/128, NQ_/128), 256, 0, stream>>>(
        peH, peL, w0bH, w0bL, bconst, Z, NQ_, PE_K, H0_DIM);

    // fused 3-layer edge MLP (R2-exact: 64-edge tiles, 2 blocks/CU)
    fused_edge<<<NE_/64, 256, 65536, stream>>>(
        xH, xL, w0aH, w0aL, w1H, w1L, w2H, w2L,
        Z, b1, b2, edges, h2);

    seg_mean<<<NQ_/8, 256, 0, stream>>>(start, h2, meanH, meanL);

    // fused pred0+pred1 (skips the g1 intermediate, 268 MB HBM saved)
    pred_fused<<<NQ_/128, 256, 0, stream>>>(
        meanH, meanL, pw0H, pw0L, pb0, pw1, pb1, out);
}